// Round 1
// baseline (491.050 us; speedup 1.0000x reference)
//
#include <hip/hip_runtime.h>
#include <cstdint>

typedef unsigned int u32;
typedef unsigned long long u64;
typedef unsigned short u16;

#define BATCH 4
#define A_CNT 70400
#define FEAT 27648
#define KSPLIT 16
#define KCHUNK 1728          // FEAT/KSPLIT
#define NTILE_IT 27          // KCHUNK/64

typedef __attribute__((ext_vector_type(8))) short bf16x8;
typedef __attribute__((ext_vector_type(4))) float f32x4;
typedef __attribute__((ext_vector_type(4))) u32 u32x4;

// ---------------- workspace layout ----------------
constexpr size_t OF_HIST = 0;                         // 4*65536*4
constexpr size_t OF_CNT  = OF_HIST + 4ull*65536*4;    // 256
constexpr size_t OF_KTH  = OF_CNT + 256;              // 256
constexpr size_t OF_KEYS = OF_KTH + 256;              // 4*70400*4 = 1126400
constexpr size_t OF_CAND = OF_KEYS + 1126400;         // 4*2048*8 = 65536
constexpr size_t OF_TBOX = OF_CAND + 65536;           // 4*1024*7*4 = 114688
constexpr size_t OF_TSC  = OF_TBOX + 114688;          // 16384
constexpr size_t OF_BX1  = OF_TSC + 16384;
constexpr size_t OF_BX2  = OF_BX1 + 16384;
constexpr size_t OF_BY1  = OF_BX2 + 16384;
constexpr size_t OF_BY2  = OF_BY1 + 16384;
constexpr size_t OF_BAR  = OF_BY2 + 16384;
constexpr size_t OF_MASK = OF_BAR + 16384;            // 4*1024*32*4 = 524288
constexpr size_t OF_ROIS = OF_MASK + 524288;          // 4*512*7*4 = 57344
constexpr size_t OF_RSC  = OF_ROIS + 57344;           // 8192
constexpr size_t OF_BSW  = OF_RSC + 8192;             // 432*32768 = 14155776
constexpr size_t OF_WT   = OF_BSW + 14155776;         // 5*65536*4 = 1310720
constexpr size_t OF_PART = OF_WT + 1310720;           // 16*2048*256*4 = 33554432
constexpr size_t OF_X1   = OF_PART + 33554432;        // 2048*256*4 = 2097152
constexpr size_t OF_X2   = OF_X1 + 2097152;
constexpr size_t OF_C1   = OF_X2 + 2097152;
constexpr size_t OF_R1   = OF_C1 + 2097152;
constexpr size_t OF_C2   = OF_R1 + 2097152;
constexpr size_t OF_R2   = OF_C2 + 2097152;
constexpr size_t WS_NEED = OF_R2 + 2097152;

// ---------------- helpers ----------------
__device__ __forceinline__ u32 keyOf(float f) {
  u32 u = __float_as_uint(f);
  return (u & 0x80000000u) ? ~u : (u | 0x80000000u);
}
__device__ __forceinline__ float keyToF(u32 k) {
  u32 u = (k & 0x80000000u) ? (k ^ 0x80000000u) : ~k;
  return __uint_as_float(u);
}
__device__ __forceinline__ u16 f2bf(float f) {   // RNE f32 -> bf16
  u32 u = __float_as_uint(f);
  u32 r = 0x7FFFu + ((u >> 16) & 1u);
  return (u16)((u + r) >> 16);
}
__device__ __forceinline__ void gload_lds16(const void* g, void* l) {
  auto gp = reinterpret_cast<const __attribute__((address_space(1))) unsigned int*>(
      reinterpret_cast<uintptr_t>(g));
  auto lp = reinterpret_cast<__attribute__((address_space(3))) unsigned int*>(
      reinterpret_cast<uintptr_t>(l));
  __builtin_amdgcn_global_load_lds(gp, lp, 16, 0, 0);
}

// ---------------- weight prep: Ws1 -> swizzled bf16 tiles; small W transposes ----------------
__global__ __launch_bounds__(256) void k_prep(const float* __restrict__ Ws1,
    const float* __restrict__ W0, const float* __restrict__ W1, const float* __restrict__ W2,
    const float* __restrict__ W3, const float* __restrict__ W4,
    u32* __restrict__ Bsw, float* __restrict__ Wt)
{
  int bid = blockIdx.x, tid = threadIdx.x;
  if (bid < 13824) {
    u32 g = (u32)bid * 256u + tid;     // u32 index into Bsw (3538944 total)
    u32 tile = g >> 13;                // /8192 u32 per 32KB tile
    u32 rem = g & 8191u;
    u32 n = rem >> 5;                  // row 0..255
    u32 p = (rem & 31u) << 2;          // byte pos in row 0..124
    u32 q = p ^ ((n & 7u) << 4);       // inverse-swizzled logical byte
    u32 col = tile * 64u + (q >> 1);
    const float* src = Ws1 + (size_t)n * FEAT + col;
    Bsw[g] = (u32)f2bf(src[0]) | ((u32)f2bf(src[1]) << 16);
  } else {
    int mb = bid - 13824;              // 0..1279
    int mat = mb >> 8;
    int o = ((mb & 255) << 8) | tid;   // 0..65535 ; o = k*256+n
    int kk = o >> 8, n = o & 255;
    const float* W = (mat == 0) ? W0 : (mat == 1) ? W1 : (mat == 2) ? W2 : (mat == 3) ? W3 : W4;
    Wt[(size_t)mat * 65536 + o] = W[n * 256 + kk];
  }
}

// ---------------- scores -> sortable keys + hi16 histogram ----------------
__global__ __launch_bounds__(256) void k_keys(const float* __restrict__ cls,
    u32* __restrict__ keys, u32* __restrict__ hist)
{
  u32 g = blockIdx.x * 256u + threadIdx.x;
  if (g >= BATCH * A_CNT) return;
  u32 b = g / A_CNT;
  float s0 = cls[(size_t)g * 3 + 0];
  float s1 = cls[(size_t)g * 3 + 1];
  float s2 = cls[(size_t)g * 3 + 2];
  u32 k = keyOf(fmaxf(s0, fmaxf(s1, s2)));
  keys[g] = k;
  atomicAdd(&hist[b * 65536u + (k >> 16)], 1u);
}

// ---------------- find hi16 threshold of the 1024th largest ----------------
__global__ __launch_bounds__(256) void k_scan(const u32* __restrict__ hist, u32* __restrict__ kth)
{
  int b = blockIdx.x, t = threadIdx.x;
  const u32* H = hist + (size_t)b * 65536;
  __shared__ u32 buf[256];
  __shared__ u32 segsuf[256];
  __shared__ int sel;
  u32 s = 0;
  for (int j = 0; j < 256; ++j) s += H[t * 256 + j];
  buf[t] = s;
  __syncthreads();
  for (int d = 1; d < 256; d <<= 1) {
    u32 v = (t + d < 256) ? buf[t + d] : 0u;
    __syncthreads();
    buf[t] += v;
    __syncthreads();
  }
  segsuf[t] = buf[t];
  __syncthreads();
  if (buf[t] >= 1024u && (t == 255 || buf[t + 1] < 1024u)) sel = t;
  __syncthreads();
  int sg = sel;
  u32 above = (sg == 255) ? 0u : segsuf[sg + 1];
  u32 bc = H[sg * 256 + t];
  __syncthreads();
  buf[t] = bc;
  __syncthreads();
  for (int d = 1; d < 256; d <<= 1) {
    u32 v = (t + d < 256) ? buf[t + d] : 0u;
    __syncthreads();
    buf[t] += v;
    __syncthreads();
  }
  u32 self = above + buf[t];
  u32 nxt = above + ((t == 255) ? 0u : buf[t + 1]);
  if (self >= 1024u && (t == 255 || nxt < 1024u)) kth[b] = (u32)(sg * 256 + t);
}

// ---------------- compact candidates (hi16 >= threshold) ----------------
__global__ __launch_bounds__(256) void k_compact(const u32* __restrict__ keys,
    const u32* __restrict__ kth, u32* __restrict__ cnt, u64* __restrict__ cand)
{
  u32 g = blockIdx.x * 256u + threadIdx.x;
  if (g >= BATCH * A_CNT) return;
  u32 b = g / A_CNT;
  u32 k = keys[g];
  if ((k >> 16) >= kth[b]) {
    u32 pos = atomicAdd(&cnt[b], 1u);
    if (pos < 2048) {
      u32 a = g - b * A_CNT;
      cand[(size_t)b * 2048 + pos] = ((u64)k << 32) | (u32)(~a);
    }
  }
}

// ---------------- bitonic sort 2048 desc; emit sorted top-1024 + NMS geometry ----------------
__global__ __launch_bounds__(1024) void k_sort(const u64* __restrict__ cand, const u32* __restrict__ cnt,
    const float* __restrict__ boxes, float* __restrict__ tbox, float* __restrict__ tsc,
    float* __restrict__ bx1, float* __restrict__ bx2, float* __restrict__ by1,
    float* __restrict__ by2, float* __restrict__ bar)
{
  int b = blockIdx.x, t = threadIdx.x;
  __shared__ u64 s[2048];
  u32 m = cnt[b]; if (m > 2048u) m = 2048u;
  for (int e = t; e < 2048; e += 1024) s[e] = (e < (int)m) ? cand[(size_t)b * 2048 + e] : 0ull;
  __syncthreads();
  for (u32 k = 2; k <= 2048; k <<= 1) {
    for (u32 j = k >> 1; j > 0; j >>= 1) {
      for (int e = t; e < 2048; e += 1024) {
        u32 p = (u32)e ^ j;
        if (p > (u32)e) {
          bool desc = ((e & k) == 0);
          u64 x = s[e], y = s[p];
          if (desc ? (x < y) : (x > y)) { s[e] = y; s[p] = x; }
        }
      }
      __syncthreads();
    }
  }
  u64 comp = s[t];
  u32 kk = (u32)(comp >> 32);
  u32 a = ~(u32)(comp & 0xFFFFFFFFull);
  int o = b * 1024 + t;
  tsc[o] = keyToF(kk);
  const float* bp = boxes + ((size_t)b * A_CNT + a) * 7;
  float x = bp[0], y = bp[1], z = bp[2], dx = bp[3], dy = bp[4], dz = bp[5], rr = bp[6];
  float* tb = tbox + (size_t)o * 7;
  tb[0] = x; tb[1] = y; tb[2] = z; tb[3] = dx; tb[4] = dy; tb[5] = dz; tb[6] = rr;
  {
#pragma clang fp contract(off)
    bx1[o] = x - 0.5f * dx; bx2[o] = x + 0.5f * dx;
    by1[o] = y - 0.5f * dy; by2[o] = y + 0.5f * dy;
    bar[o] = dx * dy;
  }
}

// ---------------- NMS suppression bitmasks ----------------
__global__ __launch_bounds__(64) void k_mask(const float* __restrict__ bx1, const float* __restrict__ bx2,
    const float* __restrict__ by1, const float* __restrict__ by2, const float* __restrict__ bar,
    u32* __restrict__ mask)
{
  int cb = blockIdx.x, rb = blockIdx.y, b = blockIdx.z;
  int t = threadIdx.x;
  int r = rb * 64 + t;
  int o = b * 1024;
  __shared__ float cx1[64], cx2[64], cy1[64], cy2[64], car[64];
  int jc0 = cb * 64;
  cx1[t] = bx1[o + jc0 + t]; cx2[t] = bx2[o + jc0 + t];
  cy1[t] = by1[o + jc0 + t]; cy2[t] = by2[o + jc0 + t];
  car[t] = bar[o + jc0 + t];
  __syncthreads();
  float rx1 = bx1[o + r], rx2 = bx2[o + r], ry1 = by1[o + r], ry2 = by2[o + r], rar = bar[o + r];
  u32 w0 = 0, w1 = 0;
  {
#pragma clang fp contract(off)
    for (int c = 0; c < 64; ++c) {
      int jc = jc0 + c;
      float iw = fminf(rx2, cx2[c]) - fmaxf(rx1, cx1[c]); iw = fmaxf(iw, 0.0f);
      float ih = fminf(ry2, cy2[c]) - fmaxf(ry1, cy1[c]); ih = fmaxf(ih, 0.0f);
      float inter = iw * ih;
      float den = fmaxf(rar + car[c] - inter, 1e-6f);
      float iou = inter / den;
      if ((iou > 0.7f) && (jc > r)) {
        if (c < 32) w0 |= 1u << c; else w1 |= 1u << (c - 32);
      }
    }
  }
  mask[((size_t)(o + r)) * 32 + cb * 2 + 0] = w0;
  mask[((size_t)(o + r)) * 32 + cb * 2 + 1] = w1;
}

// ---------------- sequential greedy NMS + compact to rois ----------------
__global__ __launch_bounds__(64) void k_nms(const u32* __restrict__ mask,
    const float* __restrict__ tbox, const float* __restrict__ tsc,
    float* __restrict__ rois, float* __restrict__ rsc)
{
  int b = blockIdx.x;
  int lane = threadIdx.x;
  const u32* M = mask + (size_t)b * 1024 * 32;
  u32 remv = 0;
  for (int i = 0; i < 1024; ++i) {
    u32 mm = (lane < 32) ? M[(size_t)i * 32 + lane] : 0u;
    u32 rw = __shfl(remv, i >> 5, 64);
    if (((rw >> (i & 31)) & 1u) == 0u) {
      if (lane < 32) remv |= mm;
    }
  }
  u32 keepw = (lane < 32) ? ~remv : 0u;
  int c = __popc(keepw);
  int pre = c;
  for (int d = 1; d < 64; d <<= 1) {
    int v = __shfl_up(pre, d, 64);
    if (lane >= d) pre += v;
  }
  int total = __shfl(pre, 31, 64);
  int base = pre - c;
  if (lane < 32) {
    u32 w = keepw;
    int rank = base;
    while (w) {
      int bit = __ffs(w) - 1;
      w &= w - 1;
      if (rank < 512) {
        int r = lane * 32 + bit;
        const float* tb = tbox + ((size_t)b * 1024 + r) * 7;
        float* rp = rois + ((size_t)b * 512 + rank) * 7;
        rp[0] = tb[0]; rp[1] = tb[1]; rp[2] = tb[2]; rp[3] = tb[3];
        rp[4] = tb[4]; rp[5] = tb[5]; rp[6] = tb[6];
        rsc[b * 512 + rank] = tsc[b * 1024 + r];
      }
      rank++;
    }
  }
  for (int z = total + lane; z < 512; z += 64) {
    float* rp = rois + ((size_t)b * 512 + z) * 7;
    rp[0] = rp[1] = rp[2] = rp[3] = rp[4] = rp[5] = rp[6] = 0.0f;
    rsc[b * 512 + z] = 0.0f;
  }
}

// ---------------- GEMM1: (2048x27648 f32) @ Ws1^T -> split-K partials ----------------
__global__ __launch_bounds__(256) void k_gemm1(const float* __restrict__ A,
    const u32* __restrict__ Bsw, float* __restrict__ part)
{
  __shared__ u32x4 Alds4[64 * 8];    // 8 KB, swizzled bf16 image
  __shared__ u32x4 Blds4[256 * 8];   // 32 KB, swizzled bf16 image
  char* Alds = (char*)Alds4;
  char* Blds = (char*)Blds4;
  int bid = blockIdx.x;
  int mt = bid & 31, ks = bid >> 5;
  int tid = threadIdx.x, lane = tid & 63, wv = tid >> 6;

  f32x4 acc[4][4];
#pragma unroll
  for (int i = 0; i < 4; ++i)
#pragma unroll
    for (int j = 0; j < 4; ++j) acc[i][j] = (f32x4){0.f, 0.f, 0.f, 0.f};

  int am = tid >> 2;
  int ak = (tid & 3) * 16;                       // element offset in 64
  const float* ap_base = A + ((size_t)(mt * 64 + am)) * FEAT + (size_t)ks * KCHUNK + ak;
  int asw = (am & 7) << 4;
  int ac0 = (tid & 3) * 32;                      // byte chunk base
  char* aw0 = Alds + am * 128 + ((ac0) ^ asw);
  char* aw1 = Alds + am * 128 + ((ac0 + 16) ^ asw);
  const char* bsrc_base = (const char*)Bsw + ((size_t)(ks * NTILE_IT)) * 32768 + (wv * 8) * 1024 + lane * 16;
  char* bdst_base = Blds + (wv * 8) * 1024;

  int row16 = lane & 15, kgrp = lane >> 4;
  int aoff[4][2], boff[4][2];
#pragma unroll
  for (int ksub = 0; ksub < 2; ++ksub) {
    int q = ksub * 64 + kgrp * 16;
#pragma unroll
    for (int mf = 0; mf < 4; ++mf) {
      int row = mf * 16 + row16;
      aoff[mf][ksub] = row * 128 + (q ^ ((row & 7) << 4));
    }
#pragma unroll
    for (int nf = 0; nf < 4; ++nf) {
      int n = wv * 64 + nf * 16 + row16;
      boff[nf][ksub] = n * 128 + (q ^ ((n & 7) << 4));
    }
  }

  for (int it = 0; it < NTILE_IT; ++it) {
    // stage A (fp32 -> bf16, swizzled ds_write)
    const float4* ap = (const float4*)(ap_base + it * 64);
    float4 f0 = ap[0], f1 = ap[1], f2 = ap[2], f3 = ap[3];
    u32x4 c0, c1;
    c0.x = (u32)f2bf(f0.x) | ((u32)f2bf(f0.y) << 16);
    c0.y = (u32)f2bf(f0.z) | ((u32)f2bf(f0.w) << 16);
    c0.z = (u32)f2bf(f1.x) | ((u32)f2bf(f1.y) << 16);
    c0.w = (u32)f2bf(f1.z) | ((u32)f2bf(f1.w) << 16);
    c1.x = (u32)f2bf(f2.x) | ((u32)f2bf(f2.y) << 16);
    c1.y = (u32)f2bf(f2.z) | ((u32)f2bf(f2.w) << 16);
    c1.z = (u32)f2bf(f3.x) | ((u32)f2bf(f3.y) << 16);
    c1.w = (u32)f2bf(f3.z) | ((u32)f2bf(f3.w) << 16);
    *(u32x4*)aw0 = c0;
    *(u32x4*)aw1 = c1;
    // stage B (pre-swizzled source -> linear LDS)
    const char* bs = bsrc_base + (size_t)it * 32768;
#pragma unroll
    for (int i = 0; i < 8; ++i) gload_lds16(bs + i * 1024, bdst_base + i * 1024);
    __syncthreads();
    // compute
    bf16x8 af[4][2], bfv[4][2];
#pragma unroll
    for (int ksub = 0; ksub < 2; ++ksub) {
#pragma unroll
      for (int mf = 0; mf < 4; ++mf) af[mf][ksub] = *(const bf16x8*)(Alds + aoff[mf][ksub]);
#pragma unroll
      for (int nf = 0; nf < 4; ++nf) bfv[nf][ksub] = *(const bf16x8*)(Blds + boff[nf][ksub]);
    }
#pragma unroll
    for (int ksub = 0; ksub < 2; ++ksub)
#pragma unroll
      for (int mf = 0; mf < 4; ++mf)
#pragma unroll
        for (int nf = 0; nf < 4; ++nf)
          acc[mf][nf] = __builtin_amdgcn_mfma_f32_16x16x32_bf16(af[mf][ksub], bfv[nf][ksub], acc[mf][nf], 0, 0, 0);
    __syncthreads();
  }
  // epilogue: write split-K partial
  float* pb = part + (size_t)ks * 524288;
#pragma unroll
  for (int mf = 0; mf < 4; ++mf) {
    int row = mt * 64 + mf * 16 + kgrp * 4;
#pragma unroll
    for (int nf = 0; nf < 4; ++nf) {
      int col = wv * 64 + nf * 16 + row16;
#pragma unroll
      for (int rr = 0; rr < 4; ++rr)
        pb[(size_t)(row + rr) * 256 + col] = acc[mf][nf][rr];
    }
  }
}

// ---------------- reduce split-K partials + BN+ReLU ----------------
__global__ __launch_bounds__(256) void k_reduce1(const float* __restrict__ part,
    const float* __restrict__ g, const float* __restrict__ bb, float* __restrict__ x)
{
  int i = blockIdx.x * 256 + threadIdx.x;   // < 524288
  float s = 0.f;
#pragma unroll
  for (int ks = 0; ks < KSPLIT; ++ks) s += part[(size_t)ks * 524288 + i];
  int n = i & 255;
  float sc = g[n] / sqrtf(1.0f + 1e-5f);
  x[i] = fmaxf(fmaf(s, sc, bb[n]), 0.0f);
}

// ---------------- small fp32 GEMM 2048x256x256 + BN+ReLU ----------------
__global__ __launch_bounds__(256) void k_small(const float* __restrict__ X, const float* __restrict__ WT,
    const float* __restrict__ g, const float* __restrict__ bb, float* __restrict__ Y)
{
  __shared__ __align__(16) float xs[8][256];
  int bid = blockIdx.x, t = threadIdx.x;
#pragma unroll
  for (int r = 0; r < 8; ++r) xs[r][t] = X[(size_t)(bid * 8 + r) * 256 + t];
  __syncthreads();
  float acc[8] = {0, 0, 0, 0, 0, 0, 0, 0};
  for (int k = 0; k < 256; k += 4) {
    float w0 = WT[(k + 0) * 256 + t];
    float w1 = WT[(k + 1) * 256 + t];
    float w2 = WT[(k + 2) * 256 + t];
    float w3 = WT[(k + 3) * 256 + t];
#pragma unroll
    for (int r = 0; r < 8; ++r) {
      float4 xv = *(const float4*)&xs[r][k];
      acc[r] = fmaf(xv.x, w0, acc[r]);
      acc[r] = fmaf(xv.y, w1, acc[r]);
      acc[r] = fmaf(xv.z, w2, acc[r]);
      acc[r] = fmaf(xv.w, w3, acc[r]);
    }
  }
  float sc = g[t] / sqrtf(1.0f + 1e-5f);
  float bv = bb[t];
#pragma unroll
  for (int r = 0; r < 8; ++r)
    Y[(size_t)(bid * 8 + r) * 256 + t] = fmaxf(fmaf(acc[r], sc, bv), 0.0f);
}

// ---------------- final heads + box decode + output assembly ----------------
__global__ __launch_bounds__(256) void k_final(const float* __restrict__ c2, const float* __restrict__ r2,
    const float* __restrict__ Wc3, const float* __restrict__ bc3,
    const float* __restrict__ Wr3, const float* __restrict__ br3,
    const float* __restrict__ rois, const float* __restrict__ rsc, float* __restrict__ out)
{
  int m = blockIdx.x * 4 + (threadIdx.x >> 6);
  int lane = threadIdx.x & 63;
  float4 cv = ((const float4*)(c2 + (size_t)m * 256))[lane];
  float4 rv = ((const float4*)(r2 + (size_t)m * 256))[lane];
  float4 wc = ((const float4*)Wc3)[lane];
  float pc = cv.x * wc.x + cv.y * wc.y + cv.z * wc.z + cv.w * wc.w;
#pragma unroll
  for (int off = 32; off > 0; off >>= 1) pc += __shfl_xor(pc, off, 64);
  float rg[7];
#pragma unroll
  for (int j = 0; j < 7; ++j) {
    float4 wr = ((const float4*)(Wr3 + j * 256))[lane];
    float p = rv.x * wr.x + rv.y * wr.y + rv.z * wr.z + rv.w * wr.w;
#pragma unroll
    for (int off = 32; off > 0; off >>= 1) p += __shfl_xor(p, off, 64);
    rg[j] = p + br3[j];
  }
  if (lane == 0) {
    float cls = pc + bc3[0];
    const float* R = rois + (size_t)m * 7;
    float rx = R[0], ry = R[1], rz = R[2], dxa = R[3], dya = R[4], dza = R[5], ra = R[6];
    float diag = sqrtf(dxa * dxa + dya * dya);
    float x = rg[0] * diag, y = rg[1] * diag, z = rg[2] * dza;
    float ex = expf(rg[3]) * dxa, ey = expf(rg[4]) * dya, ez = expf(rg[5]) * dza;
    float hr = rg[6] + ra;
    float cc = cosf(ra), sn = sinf(ra);
    float xr = x * cc - y * sn, yr = x * sn + y * cc;
    float* O = out + (size_t)m * 9;
    O[0] = cls; O[1] = xr + rx; O[2] = yr + ry; O[3] = z + rz;
    O[4] = ex; O[5] = ey; O[6] = ez; O[7] = hr; O[8] = rsc[m];
  }
}

// ---------------- launch ----------------
extern "C" void kernel_launch(void* const* d_in, const int* in_sizes, int n_in,
                              void* d_out, int out_size, void* d_ws, size_t ws_size,
                              hipStream_t stream)
{
  const float* rpn_box = (const float*)d_in[0];
  const float* rpn_cls = (const float*)d_in[1];
  const float* pooled  = (const float*)d_in[2];
  const float* Ws1 = (const float*)d_in[3];
  const float* g1  = (const float*)d_in[4];
  const float* b1  = (const float*)d_in[5];
  const float* Ws2 = (const float*)d_in[6];
  const float* g2  = (const float*)d_in[7];
  const float* b2  = (const float*)d_in[8];
  const float* Wc1 = (const float*)d_in[9];
  const float* gc1 = (const float*)d_in[10];
  const float* bc1 = (const float*)d_in[11];
  const float* Wc2 = (const float*)d_in[12];
  const float* gc2 = (const float*)d_in[13];
  const float* bc2 = (const float*)d_in[14];
  const float* Wc3 = (const float*)d_in[15];
  const float* bc3 = (const float*)d_in[16];
  const float* Wr1 = (const float*)d_in[17];
  const float* gr1 = (const float*)d_in[18];
  const float* br1 = (const float*)d_in[19];
  const float* Wr2 = (const float*)d_in[20];
  const float* gr2 = (const float*)d_in[21];
  const float* br2 = (const float*)d_in[22];
  const float* Wr3 = (const float*)d_in[23];
  const float* br3 = (const float*)d_in[24];

  if (ws_size < WS_NEED) return;  // workspace insufficient (would need fallback)

  char* ws = (char*)d_ws;
  u32* hist = (u32*)(ws + OF_HIST);
  u32* cnt  = (u32*)(ws + OF_CNT);
  u32* kth  = (u32*)(ws + OF_KTH);
  u32* keys = (u32*)(ws + OF_KEYS);
  u64* cand = (u64*)(ws + OF_CAND);
  float* tbox = (float*)(ws + OF_TBOX);
  float* tsc  = (float*)(ws + OF_TSC);
  float* bx1 = (float*)(ws + OF_BX1);
  float* bx2 = (float*)(ws + OF_BX2);
  float* by1 = (float*)(ws + OF_BY1);
  float* by2 = (float*)(ws + OF_BY2);
  float* bar = (float*)(ws + OF_BAR);
  u32* mask = (u32*)(ws + OF_MASK);
  float* roisb = (float*)(ws + OF_ROIS);
  float* rscb  = (float*)(ws + OF_RSC);
  u32* Bsw = (u32*)(ws + OF_BSW);
  float* Wt = (float*)(ws + OF_WT);
  float* part = (float*)(ws + OF_PART);
  float* x1 = (float*)(ws + OF_X1);
  float* x2 = (float*)(ws + OF_X2);
  float* c1 = (float*)(ws + OF_C1);
  float* r1 = (float*)(ws + OF_R1);
  float* c2 = (float*)(ws + OF_C2);
  float* r2 = (float*)(ws + OF_R2);

  hipMemsetAsync(ws + OF_HIST, 0, 4ull * 65536 * 4 + 256, stream);

  k_prep<<<15104, 256, 0, stream>>>(Ws1, Ws2, Wc1, Wc2, Wr1, Wr2, Bsw, Wt);
  k_keys<<<1100, 256, 0, stream>>>(rpn_cls, keys, hist);
  k_scan<<<4, 256, 0, stream>>>(hist, kth);
  k_compact<<<1100, 256, 0, stream>>>(keys, kth, cnt, cand);
  k_sort<<<4, 1024, 0, stream>>>(cand, cnt, rpn_box, tbox, tsc, bx1, bx2, by1, by2, bar);
  k_mask<<<dim3(16, 16, 4), 64, 0, stream>>>(bx1, bx2, by1, by2, bar, mask);
  k_nms<<<4, 64, 0, stream>>>(mask, tbox, tsc, roisb, rscb);

  k_gemm1<<<512, 256, 0, stream>>>(pooled, Bsw, part);
  k_reduce1<<<2048, 256, 0, stream>>>(part, g1, b1, x1);
  k_small<<<256, 256, 0, stream>>>(x1, Wt + 0 * 65536, g2, b2, x2);
  k_small<<<256, 256, 0, stream>>>(x2, Wt + 1 * 65536, gc1, bc1, c1);
  k_small<<<256, 256, 0, stream>>>(x2, Wt + 3 * 65536, gr1, br1, r1);
  k_small<<<256, 256, 0, stream>>>(c1, Wt + 2 * 65536, gc2, bc2, c2);
  k_small<<<256, 256, 0, stream>>>(r1, Wt + 4 * 65536, gr2, br2, r2);
  k_final<<<512, 256, 0, stream>>>(c2, r2, Wc3, bc3, Wr3, br3, roisb, rscb, (float*)d_out);
}

// Round 2
// 373.768 us; speedup vs baseline: 1.3138x; 1.3138x over previous
//
#include <hip/hip_runtime.h>
#include <cstdint>

typedef unsigned int u32;
typedef unsigned long long u64;
typedef unsigned short u16;

#define BATCH 4
#define A_CNT 70400
#define FEAT 27648
#define KSPLIT 16
#define KCHUNK 1728          // FEAT/KSPLIT
#define NTILE_IT 27          // KCHUNK/64

typedef __attribute__((ext_vector_type(8))) short bf16x8;
typedef __attribute__((ext_vector_type(4))) float f32x4;
typedef __attribute__((ext_vector_type(4))) u32 u32x4;

// ---------------- workspace layout ----------------
constexpr size_t OF_HIST = 0;                         // 4*65536*4
constexpr size_t OF_CNT  = OF_HIST + 4ull*65536*4;    // 256
constexpr size_t OF_KTH  = OF_CNT + 256;              // 256
constexpr size_t OF_KEYS = OF_KTH + 256;              // 4*70400*4 = 1126400
constexpr size_t OF_CAND = OF_KEYS + 1126400;         // 4*2048*8 = 65536
constexpr size_t OF_TBOX = OF_CAND + 65536;           // 4*1024*7*4 = 114688
constexpr size_t OF_TSC  = OF_TBOX + 114688;          // 16384
constexpr size_t OF_BX1  = OF_TSC + 16384;
constexpr size_t OF_BX2  = OF_BX1 + 16384;
constexpr size_t OF_BY1  = OF_BX2 + 16384;
constexpr size_t OF_BY2  = OF_BY1 + 16384;
constexpr size_t OF_BAR  = OF_BY2 + 16384;
constexpr size_t OF_MASK = OF_BAR + 16384;            // 4*1024*32*4 = 524288
constexpr size_t OF_ROIS = OF_MASK + 524288;          // 4*512*7*4 = 57344
constexpr size_t OF_RSC  = OF_ROIS + 57344;           // 8192
constexpr size_t OF_BSW  = OF_RSC + 8192;             // 432*32768 = 14155776
constexpr size_t OF_WT   = OF_BSW + 14155776;         // 5*65536*4 = 1310720
constexpr size_t OF_PART = OF_WT + 1310720;           // 16*2048*256*4 = 33554432
constexpr size_t OF_X1   = OF_PART + 33554432;        // 2048*256*4 = 2097152
constexpr size_t OF_X2   = OF_X1 + 2097152;
constexpr size_t OF_C1   = OF_X2 + 2097152;
constexpr size_t OF_R1   = OF_C1 + 2097152;
constexpr size_t OF_C2   = OF_R1 + 2097152;
constexpr size_t OF_R2   = OF_C2 + 2097152;
constexpr size_t WS_NEED = OF_R2 + 2097152;

// ---------------- helpers ----------------
__device__ __forceinline__ u32 keyOf(float f) {
  u32 u = __float_as_uint(f);
  return (u & 0x80000000u) ? ~u : (u | 0x80000000u);
}
__device__ __forceinline__ float keyToF(u32 k) {
  u32 u = (k & 0x80000000u) ? (k ^ 0x80000000u) : ~k;
  return __uint_as_float(u);
}
__device__ __forceinline__ u16 f2bf(float f) {   // RNE f32 -> bf16
  u32 u = __float_as_uint(f);
  u32 r = 0x7FFFu + ((u >> 16) & 1u);
  return (u16)((u + r) >> 16);
}
__device__ __forceinline__ void gload_lds16(const void* g, void* l) {
  auto gp = reinterpret_cast<const __attribute__((address_space(1))) unsigned int*>(
      reinterpret_cast<uintptr_t>(g));
  auto lp = reinterpret_cast<__attribute__((address_space(3))) unsigned int*>(
      reinterpret_cast<uintptr_t>(l));
  __builtin_amdgcn_global_load_lds(gp, lp, 16, 0, 0);
}

// ---------------- weight prep: Ws1 -> swizzled bf16 tiles; small W transposes ----------------
__global__ __launch_bounds__(256) void k_prep(const float* __restrict__ Ws1,
    const float* __restrict__ W0, const float* __restrict__ W1, const float* __restrict__ W2,
    const float* __restrict__ W3, const float* __restrict__ W4,
    u32* __restrict__ Bsw, float* __restrict__ Wt)
{
  int bid = blockIdx.x, tid = threadIdx.x;
  if (bid < 13824) {
    u32 g = (u32)bid * 256u + tid;     // u32 index into Bsw (3538944 total)
    u32 tile = g >> 13;                // /8192 u32 per 32KB tile
    u32 rem = g & 8191u;
    u32 n = rem >> 5;                  // row 0..255
    u32 p = (rem & 31u) << 2;          // byte pos in row 0..124
    u32 q = p ^ ((n & 7u) << 4);       // inverse-swizzled logical byte
    u32 col = tile * 64u + (q >> 1);
    const float* src = Ws1 + (size_t)n * FEAT + col;
    Bsw[g] = (u32)f2bf(src[0]) | ((u32)f2bf(src[1]) << 16);
  } else {
    int mb = bid - 13824;              // 0..1279
    int mat = mb >> 8;
    int o = ((mb & 255) << 8) | tid;   // 0..65535 ; o = k*256+n
    int kk = o >> 8, n = o & 255;
    const float* W = (mat == 0) ? W0 : (mat == 1) ? W1 : (mat == 2) ? W2 : (mat == 3) ? W3 : W4;
    Wt[(size_t)mat * 65536 + o] = W[n * 256 + kk];
  }
}

// ---------------- scores -> sortable keys + hi16 histogram ----------------
__global__ __launch_bounds__(256) void k_keys(const float* __restrict__ cls,
    u32* __restrict__ keys, u32* __restrict__ hist)
{
  u32 g = blockIdx.x * 256u + threadIdx.x;
  if (g >= BATCH * A_CNT) return;
  u32 b = g / A_CNT;
  float s0 = cls[(size_t)g * 3 + 0];
  float s1 = cls[(size_t)g * 3 + 1];
  float s2 = cls[(size_t)g * 3 + 2];
  u32 k = keyOf(fmaxf(s0, fmaxf(s1, s2)));
  keys[g] = k;
  atomicAdd(&hist[b * 65536u + (k >> 16)], 1u);
}

// ---------------- find hi16 threshold of the 1024th largest ----------------
__global__ __launch_bounds__(256) void k_scan(const u32* __restrict__ hist, u32* __restrict__ kth)
{
  int b = blockIdx.x, t = threadIdx.x;
  const u32* H = hist + (size_t)b * 65536;
  __shared__ u32 buf[256];
  __shared__ u32 segsuf[256];
  __shared__ int sel;
  u32 s = 0;
  for (int j = 0; j < 256; ++j) s += H[t * 256 + j];
  buf[t] = s;
  __syncthreads();
  for (int d = 1; d < 256; d <<= 1) {
    u32 v = (t + d < 256) ? buf[t + d] : 0u;
    __syncthreads();
    buf[t] += v;
    __syncthreads();
  }
  segsuf[t] = buf[t];
  __syncthreads();
  if (buf[t] >= 1024u && (t == 255 || buf[t + 1] < 1024u)) sel = t;
  __syncthreads();
  int sg = sel;
  u32 above = (sg == 255) ? 0u : segsuf[sg + 1];
  u32 bc = H[sg * 256 + t];
  __syncthreads();
  buf[t] = bc;
  __syncthreads();
  for (int d = 1; d < 256; d <<= 1) {
    u32 v = (t + d < 256) ? buf[t + d] : 0u;
    __syncthreads();
    buf[t] += v;
    __syncthreads();
  }
  u32 self = above + buf[t];
  u32 nxt = above + ((t == 255) ? 0u : buf[t + 1]);
  if (self >= 1024u && (t == 255 || nxt < 1024u)) kth[b] = (u32)(sg * 256 + t);
}

// ---------------- compact candidates (hi16 >= threshold) ----------------
__global__ __launch_bounds__(256) void k_compact(const u32* __restrict__ keys,
    const u32* __restrict__ kth, u32* __restrict__ cnt, u64* __restrict__ cand)
{
  u32 g = blockIdx.x * 256u + threadIdx.x;
  if (g >= BATCH * A_CNT) return;
  u32 b = g / A_CNT;
  u32 k = keys[g];
  if ((k >> 16) >= kth[b]) {
    u32 pos = atomicAdd(&cnt[b], 1u);
    if (pos < 2048) {
      u32 a = g - b * A_CNT;
      cand[(size_t)b * 2048 + pos] = ((u64)k << 32) | (u32)(~a);
    }
  }
}

// ---------------- bitonic sort 2048 desc; emit sorted top-1024 + NMS geometry ----------------
__global__ __launch_bounds__(1024) void k_sort(const u64* __restrict__ cand, const u32* __restrict__ cnt,
    const float* __restrict__ boxes, float* __restrict__ tbox, float* __restrict__ tsc,
    float* __restrict__ bx1, float* __restrict__ bx2, float* __restrict__ by1,
    float* __restrict__ by2, float* __restrict__ bar)
{
  int b = blockIdx.x, t = threadIdx.x;
  __shared__ u64 s[2048];
  u32 m = cnt[b]; if (m > 2048u) m = 2048u;
  for (int e = t; e < 2048; e += 1024) s[e] = (e < (int)m) ? cand[(size_t)b * 2048 + e] : 0ull;
  __syncthreads();
  for (u32 k = 2; k <= 2048; k <<= 1) {
    for (u32 j = k >> 1; j > 0; j >>= 1) {
      for (int e = t; e < 2048; e += 1024) {
        u32 p = (u32)e ^ j;
        if (p > (u32)e) {
          bool desc = ((e & k) == 0);
          u64 x = s[e], y = s[p];
          if (desc ? (x < y) : (x > y)) { s[e] = y; s[p] = x; }
        }
      }
      __syncthreads();
    }
  }
  u64 comp = s[t];
  u32 kk = (u32)(comp >> 32);
  u32 a = ~(u32)(comp & 0xFFFFFFFFull);
  int o = b * 1024 + t;
  tsc[o] = keyToF(kk);
  const float* bp = boxes + ((size_t)b * A_CNT + a) * 7;
  float x = bp[0], y = bp[1], z = bp[2], dx = bp[3], dy = bp[4], dz = bp[5], rr = bp[6];
  float* tb = tbox + (size_t)o * 7;
  tb[0] = x; tb[1] = y; tb[2] = z; tb[3] = dx; tb[4] = dy; tb[5] = dz; tb[6] = rr;
  {
#pragma clang fp contract(off)
    bx1[o] = x - 0.5f * dx; bx2[o] = x + 0.5f * dx;
    by1[o] = y - 0.5f * dy; by2[o] = y + 0.5f * dy;
    bar[o] = dx * dy;
  }
}

// ---------------- NMS suppression bitmasks ----------------
__global__ __launch_bounds__(64) void k_mask(const float* __restrict__ bx1, const float* __restrict__ bx2,
    const float* __restrict__ by1, const float* __restrict__ by2, const float* __restrict__ bar,
    u32* __restrict__ mask)
{
  int cb = blockIdx.x, rb = blockIdx.y, b = blockIdx.z;
  int t = threadIdx.x;
  int r = rb * 64 + t;
  int o = b * 1024;
  __shared__ float cx1[64], cx2[64], cy1[64], cy2[64], car[64];
  int jc0 = cb * 64;
  cx1[t] = bx1[o + jc0 + t]; cx2[t] = bx2[o + jc0 + t];
  cy1[t] = by1[o + jc0 + t]; cy2[t] = by2[o + jc0 + t];
  car[t] = bar[o + jc0 + t];
  __syncthreads();
  float rx1 = bx1[o + r], rx2 = bx2[o + r], ry1 = by1[o + r], ry2 = by2[o + r], rar = bar[o + r];
  u32 w0 = 0, w1 = 0;
  {
#pragma clang fp contract(off)
    for (int c = 0; c < 64; ++c) {
      int jc = jc0 + c;
      float iw = fminf(rx2, cx2[c]) - fmaxf(rx1, cx1[c]); iw = fmaxf(iw, 0.0f);
      float ih = fminf(ry2, cy2[c]) - fmaxf(ry1, cy1[c]); ih = fmaxf(ih, 0.0f);
      float inter = iw * ih;
      float den = fmaxf(rar + car[c] - inter, 1e-6f);
      float iou = inter / den;
      if ((iou > 0.7f) && (jc > r)) {
        if (c < 32) w0 |= 1u << c; else w1 |= 1u << (c - 32);
      }
    }
  }
  mask[((size_t)(o + r)) * 32 + cb * 2 + 0] = w0;
  mask[((size_t)(o + r)) * 32 + cb * 2 + 1] = w1;
}

// ---------------- chunked sequential greedy NMS + compact to rois ----------------
// Exact reformulation of: for i in order: if !removed[i]: removed |= mask[i].
// Lane l<32 owns removal word R (columns 32l..32l+31). Rows processed in 32
// chunks of 32; chunk's self-column recurrence is lane-local in lane c (its
// registers hold exactly M[(c*32+i)*32+c]); mask words prefetched 1 chunk
// ahead into statically-indexed registers (addresses independent of R).
__global__ __launch_bounds__(64) void k_nms(const u32* __restrict__ mask,
    const float* __restrict__ tbox, const float* __restrict__ tsc,
    float* __restrict__ rois, float* __restrict__ rsc)
{
  int b = blockIdx.x;
  int lane = threadIdx.x;
  int el = lane & 31;
  const u32* M = mask + (size_t)b * 1024 * 32;
  u32 R = 0;
  u32 cur[32], nxt[32];
#pragma unroll
  for (int i = 0; i < 32; ++i) cur[i] = M[(size_t)(i * 32 + el)];
#pragma unroll 1
  for (int c = 0; c < 32; ++c) {
    // prefetch chunk c+1 words (hidden under this chunk's VALU body)
    if (c < 31) {
      int nb = (c + 1) * 1024 + el;
#pragma unroll
      for (int i = 0; i < 32; ++i) nxt[i] = M[(size_t)(nb + i * 32)];
    }
    // intra-chunk recurrence (valid in lane c; other lanes compute garbage)
    u32 w = R;
#pragma unroll
    for (int i = 0; i < 32; ++i) w |= ((w >> i) & 1u) ? 0u : cur[i];
    u32 wfin = __shfl(w, c, 64);
    // apply surviving rows' masks to all columns (mask bits only where j > r,
    // so OR is exact; lane c's result equals wfin by construction)
#pragma unroll
    for (int i = 0; i < 32; ++i) R |= ((wfin >> i) & 1u) ? 0u : cur[i];
#pragma unroll
    for (int i = 0; i < 32; ++i) cur[i] = nxt[i];
  }
  u32 keepw = (lane < 32) ? ~R : 0u;
  int c = __popc(keepw);
  int pre = c;
  for (int d = 1; d < 64; d <<= 1) {
    int v = __shfl_up(pre, d, 64);
    if (lane >= d) pre += v;
  }
  int total = __shfl(pre, 31, 64);
  int base = pre - c;
  if (lane < 32) {
    u32 w = keepw;
    int rank = base;
    while (w) {
      int bit = __ffs(w) - 1;
      w &= w - 1;
      if (rank < 512) {
        int r = lane * 32 + bit;
        const float* tb = tbox + ((size_t)b * 1024 + r) * 7;
        float* rp = rois + ((size_t)b * 512 + rank) * 7;
        rp[0] = tb[0]; rp[1] = tb[1]; rp[2] = tb[2]; rp[3] = tb[3];
        rp[4] = tb[4]; rp[5] = tb[5]; rp[6] = tb[6];
        rsc[b * 512 + rank] = tsc[b * 1024 + r];
      }
      rank++;
    }
  }
  for (int z = total + lane; z < 512; z += 64) {
    float* rp = rois + ((size_t)b * 512 + z) * 7;
    rp[0] = rp[1] = rp[2] = rp[3] = rp[4] = rp[5] = rp[6] = 0.0f;
    rsc[b * 512 + z] = 0.0f;
  }
}

// ---------------- GEMM1: (2048x27648 f32) @ Ws1^T -> split-K partials ----------------
__global__ __launch_bounds__(256) void k_gemm1(const float* __restrict__ A,
    const u32* __restrict__ Bsw, float* __restrict__ part)
{
  __shared__ u32x4 Alds4[64 * 8];    // 8 KB, swizzled bf16 image
  __shared__ u32x4 Blds4[256 * 8];   // 32 KB, swizzled bf16 image
  char* Alds = (char*)Alds4;
  char* Blds = (char*)Blds4;
  int bid = blockIdx.x;
  int mt = bid & 31, ks = bid >> 5;
  int tid = threadIdx.x, lane = tid & 63, wv = tid >> 6;

  f32x4 acc[4][4];
#pragma unroll
  for (int i = 0; i < 4; ++i)
#pragma unroll
    for (int j = 0; j < 4; ++j) acc[i][j] = (f32x4){0.f, 0.f, 0.f, 0.f};

  int am = tid >> 2;
  int ak = (tid & 3) * 16;                       // element offset in 64
  const float* ap_base = A + ((size_t)(mt * 64 + am)) * FEAT + (size_t)ks * KCHUNK + ak;
  int asw = (am & 7) << 4;
  int ac0 = (tid & 3) * 32;                      // byte chunk base
  char* aw0 = Alds + am * 128 + ((ac0) ^ asw);
  char* aw1 = Alds + am * 128 + ((ac0 + 16) ^ asw);
  const char* bsrc_base = (const char*)Bsw + ((size_t)(ks * NTILE_IT)) * 32768 + (wv * 8) * 1024 + lane * 16;
  char* bdst_base = Blds + (wv * 8) * 1024;

  int row16 = lane & 15, kgrp = lane >> 4;
  int aoff[4][2], boff[4][2];
#pragma unroll
  for (int ksub = 0; ksub < 2; ++ksub) {
    int q = ksub * 64 + kgrp * 16;
#pragma unroll
    for (int mf = 0; mf < 4; ++mf) {
      int row = mf * 16 + row16;
      aoff[mf][ksub] = row * 128 + (q ^ ((row & 7) << 4));
    }
#pragma unroll
    for (int nf = 0; nf < 4; ++nf) {
      int n = wv * 64 + nf * 16 + row16;
      boff[nf][ksub] = n * 128 + (q ^ ((n & 7) << 4));
    }
  }

  for (int it = 0; it < NTILE_IT; ++it) {
    // stage A (fp32 -> bf16, swizzled ds_write)
    const float4* ap = (const float4*)(ap_base + it * 64);
    float4 f0 = ap[0], f1 = ap[1], f2 = ap[2], f3 = ap[3];
    u32x4 c0, c1;
    c0.x = (u32)f2bf(f0.x) | ((u32)f2bf(f0.y) << 16);
    c0.y = (u32)f2bf(f0.z) | ((u32)f2bf(f0.w) << 16);
    c0.z = (u32)f2bf(f1.x) | ((u32)f2bf(f1.y) << 16);
    c0.w = (u32)f2bf(f1.z) | ((u32)f2bf(f1.w) << 16);
    c1.x = (u32)f2bf(f2.x) | ((u32)f2bf(f2.y) << 16);
    c1.y = (u32)f2bf(f2.z) | ((u32)f2bf(f2.w) << 16);
    c1.z = (u32)f2bf(f3.x) | ((u32)f2bf(f3.y) << 16);
    c1.w = (u32)f2bf(f3.z) | ((u32)f2bf(f3.w) << 16);
    *(u32x4*)aw0 = c0;
    *(u32x4*)aw1 = c1;
    // stage B (pre-swizzled source -> linear LDS)
    const char* bs = bsrc_base + (size_t)it * 32768;
#pragma unroll
    for (int i = 0; i < 8; ++i) gload_lds16(bs + i * 1024, bdst_base + i * 1024);
    __syncthreads();
    // compute
    bf16x8 af[4][2], bfv[4][2];
#pragma unroll
    for (int ksub = 0; ksub < 2; ++ksub) {
#pragma unroll
      for (int mf = 0; mf < 4; ++mf) af[mf][ksub] = *(const bf16x8*)(Alds + aoff[mf][ksub]);
#pragma unroll
      for (int nf = 0; nf < 4; ++nf) bfv[nf][ksub] = *(const bf16x8*)(Blds + boff[nf][ksub]);
    }
#pragma unroll
    for (int ksub = 0; ksub < 2; ++ksub)
#pragma unroll
      for (int mf = 0; mf < 4; ++mf)
#pragma unroll
        for (int nf = 0; nf < 4; ++nf)
          acc[mf][nf] = __builtin_amdgcn_mfma_f32_16x16x32_bf16(af[mf][ksub], bfv[nf][ksub], acc[mf][nf], 0, 0, 0);
    __syncthreads();
  }
  // epilogue: write split-K partial
  float* pb = part + (size_t)ks * 524288;
#pragma unroll
  for (int mf = 0; mf < 4; ++mf) {
    int row = mt * 64 + mf * 16 + kgrp * 4;
#pragma unroll
    for (int nf = 0; nf < 4; ++nf) {
      int col = wv * 64 + nf * 16 + row16;
#pragma unroll
      for (int rr = 0; rr < 4; ++rr)
        pb[(size_t)(row + rr) * 256 + col] = acc[mf][nf][rr];
    }
  }
}

// ---------------- reduce split-K partials + BN+ReLU ----------------
__global__ __launch_bounds__(256) void k_reduce1(const float* __restrict__ part,
    const float* __restrict__ g, const float* __restrict__ bb, float* __restrict__ x)
{
  int i = blockIdx.x * 256 + threadIdx.x;   // < 524288
  float s = 0.f;
#pragma unroll
  for (int ks = 0; ks < KSPLIT; ++ks) s += part[(size_t)ks * 524288 + i];
  int n = i & 255;
  float sc = g[n] / sqrtf(1.0f + 1e-5f);
  x[i] = fmaxf(fmaf(s, sc, bb[n]), 0.0f);
}

// ---------------- small fp32 GEMM 2048x256x256 + BN+ReLU ----------------
__global__ __launch_bounds__(256) void k_small(const float* __restrict__ X, const float* __restrict__ WT,
    const float* __restrict__ g, const float* __restrict__ bb, float* __restrict__ Y)
{
  __shared__ __align__(16) float xs[8][256];
  int bid = blockIdx.x, t = threadIdx.x;
#pragma unroll
  for (int r = 0; r < 8; ++r) xs[r][t] = X[(size_t)(bid * 8 + r) * 256 + t];
  __syncthreads();
  float acc[8] = {0, 0, 0, 0, 0, 0, 0, 0};
  for (int k = 0; k < 256; k += 4) {
    float w0 = WT[(k + 0) * 256 + t];
    float w1 = WT[(k + 1) * 256 + t];
    float w2 = WT[(k + 2) * 256 + t];
    float w3 = WT[(k + 3) * 256 + t];
#pragma unroll
    for (int r = 0; r < 8; ++r) {
      float4 xv = *(const float4*)&xs[r][k];
      acc[r] = fmaf(xv.x, w0, acc[r]);
      acc[r] = fmaf(xv.y, w1, acc[r]);
      acc[r] = fmaf(xv.z, w2, acc[r]);
      acc[r] = fmaf(xv.w, w3, acc[r]);
    }
  }
  float sc = g[t] / sqrtf(1.0f + 1e-5f);
  float bv = bb[t];
#pragma unroll
  for (int r = 0; r < 8; ++r)
    Y[(size_t)(bid * 8 + r) * 256 + t] = fmaxf(fmaf(acc[r], sc, bv), 0.0f);
}

// ---------------- final heads + box decode + output assembly ----------------
__global__ __launch_bounds__(256) void k_final(const float* __restrict__ c2, const float* __restrict__ r2,
    const float* __restrict__ Wc3, const float* __restrict__ bc3,
    const float* __restrict__ Wr3, const float* __restrict__ br3,
    const float* __restrict__ rois, const float* __restrict__ rsc, float* __restrict__ out)
{
  int m = blockIdx.x * 4 + (threadIdx.x >> 6);
  int lane = threadIdx.x & 63;
  float4 cv = ((const float4*)(c2 + (size_t)m * 256))[lane];
  float4 rv = ((const float4*)(r2 + (size_t)m * 256))[lane];
  float4 wc = ((const float4*)Wc3)[lane];
  float pc = cv.x * wc.x + cv.y * wc.y + cv.z * wc.z + cv.w * wc.w;
#pragma unroll
  for (int off = 32; off > 0; off >>= 1) pc += __shfl_xor(pc, off, 64);
  float rg[7];
#pragma unroll
  for (int j = 0; j < 7; ++j) {
    float4 wr = ((const float4*)(Wr3 + j * 256))[lane];
    float p = rv.x * wr.x + rv.y * wr.y + rv.z * wr.z + rv.w * wr.w;
#pragma unroll
    for (int off = 32; off > 0; off >>= 1) p += __shfl_xor(p, off, 64);
    rg[j] = p + br3[j];
  }
  if (lane == 0) {
    float cls = pc + bc3[0];
    const float* R = rois + (size_t)m * 7;
    float rx = R[0], ry = R[1], rz = R[2], dxa = R[3], dya = R[4], dza = R[5], ra = R[6];
    float diag = sqrtf(dxa * dxa + dya * dya);
    float x = rg[0] * diag, y = rg[1] * diag, z = rg[2] * dza;
    float ex = expf(rg[3]) * dxa, ey = expf(rg[4]) * dya, ez = expf(rg[5]) * dza;
    float hr = rg[6] + ra;
    float cc = cosf(ra), sn = sinf(ra);
    float xr = x * cc - y * sn, yr = x * sn + y * cc;
    float* O = out + (size_t)m * 9;
    O[0] = cls; O[1] = xr + rx; O[2] = yr + ry; O[3] = z + rz;
    O[4] = ex; O[5] = ey; O[6] = ez; O[7] = hr; O[8] = rsc[m];
  }
}

// ---------------- launch ----------------
extern "C" void kernel_launch(void* const* d_in, const int* in_sizes, int n_in,
                              void* d_out, int out_size, void* d_ws, size_t ws_size,
                              hipStream_t stream)
{
  const float* rpn_box = (const float*)d_in[0];
  const float* rpn_cls = (const float*)d_in[1];
  const float* pooled  = (const float*)d_in[2];
  const float* Ws1 = (const float*)d_in[3];
  const float* g1  = (const float*)d_in[4];
  const float* b1  = (const float*)d_in[5];
  const float* Ws2 = (const float*)d_in[6];
  const float* g2  = (const float*)d_in[7];
  const float* b2  = (const float*)d_in[8];
  const float* Wc1 = (const float*)d_in[9];
  const float* gc1 = (const float*)d_in[10];
  const float* bc1 = (const float*)d_in[11];
  const float* Wc2 = (const float*)d_in[12];
  const float* gc2 = (const float*)d_in[13];
  const float* bc2 = (const float*)d_in[14];
  const float* Wc3 = (const float*)d_in[15];
  const float* bc3 = (const float*)d_in[16];
  const float* Wr1 = (const float*)d_in[17];
  const float* gr1 = (const float*)d_in[18];
  const float* br1 = (const float*)d_in[19];
  const float* Wr2 = (const float*)d_in[20];
  const float* gr2 = (const float*)d_in[21];
  const float* br2 = (const float*)d_in[22];
  const float* Wr3 = (const float*)d_in[23];
  const float* br3 = (const float*)d_in[24];

  if (ws_size < WS_NEED) return;  // workspace insufficient (would need fallback)

  char* ws = (char*)d_ws;
  u32* hist = (u32*)(ws + OF_HIST);
  u32* cnt  = (u32*)(ws + OF_CNT);
  u32* kth  = (u32*)(ws + OF_KTH);
  u32* keys = (u32*)(ws + OF_KEYS);
  u64* cand = (u64*)(ws + OF_CAND);
  float* tbox = (float*)(ws + OF_TBOX);
  float* tsc  = (float*)(ws + OF_TSC);
  float* bx1 = (float*)(ws + OF_BX1);
  float* bx2 = (float*)(ws + OF_BX2);
  float* by1 = (float*)(ws + OF_BY1);
  float* by2 = (float*)(ws + OF_BY2);
  float* bar = (float*)(ws + OF_BAR);
  u32* mask = (u32*)(ws + OF_MASK);
  float* roisb = (float*)(ws + OF_ROIS);
  float* rscb  = (float*)(ws + OF_RSC);
  u32* Bsw = (u32*)(ws + OF_BSW);
  float* Wt = (float*)(ws + OF_WT);
  float* part = (float*)(ws + OF_PART);
  float* x1 = (float*)(ws + OF_X1);
  float* x2 = (float*)(ws + OF_X2);
  float* c1 = (float*)(ws + OF_C1);
  float* r1 = (float*)(ws + OF_R1);
  float* c2 = (float*)(ws + OF_C2);
  float* r2 = (float*)(ws + OF_R2);

  hipMemsetAsync(ws + OF_HIST, 0, 4ull * 65536 * 4 + 256, stream);

  k_prep<<<15104, 256, 0, stream>>>(Ws1, Ws2, Wc1, Wc2, Wr1, Wr2, Bsw, Wt);
  k_keys<<<1100, 256, 0, stream>>>(rpn_cls, keys, hist);
  k_scan<<<4, 256, 0, stream>>>(hist, kth);
  k_compact<<<1100, 256, 0, stream>>>(keys, kth, cnt, cand);
  k_sort<<<4, 1024, 0, stream>>>(cand, cnt, rpn_box, tbox, tsc, bx1, bx2, by1, by2, bar);
  k_mask<<<dim3(16, 16, 4), 64, 0, stream>>>(bx1, bx2, by1, by2, bar, mask);
  k_nms<<<4, 64, 0, stream>>>(mask, tbox, tsc, roisb, rscb);

  k_gemm1<<<512, 256, 0, stream>>>(pooled, Bsw, part);
  k_reduce1<<<2048, 256, 0, stream>>>(part, g1, b1, x1);
  k_small<<<256, 256, 0, stream>>>(x1, Wt + 0 * 65536, g2, b2, x2);
  k_small<<<256, 256, 0, stream>>>(x2, Wt + 1 * 65536, gc1, bc1, c1);
  k_small<<<256, 256, 0, stream>>>(x2, Wt + 3 * 65536, gr1, br1, r1);
  k_small<<<256, 256, 0, stream>>>(c1, Wt + 2 * 65536, gc2, bc2, c2);
  k_small<<<256, 256, 0, stream>>>(r1, Wt + 4 * 65536, gr2, br2, r2);
  k_final<<<512, 256, 0, stream>>>(c2, r2, Wc3, bc3, Wr3, br3, roisb, rscb, (float*)d_out);
}

// Round 3
// 373.535 us; speedup vs baseline: 1.3146x; 1.0006x over previous
//
#include <hip/hip_runtime.h>
#include <cstdint>

typedef unsigned int u32;
typedef unsigned long long u64;
typedef unsigned short u16;

#define BATCH 4
#define A_CNT 70400
#define FEAT 27648
#define KSPLIT 16
#define KCHUNK 1728          // FEAT/KSPLIT
#define NTILE_IT 27          // KCHUNK/64

typedef __attribute__((ext_vector_type(8))) short bf16x8;
typedef __attribute__((ext_vector_type(4))) float f32x4;
typedef __attribute__((ext_vector_type(4))) u32 u32x4;

// ---------------- workspace layout ----------------
constexpr size_t OF_HIST = 0;                         // 4*65536*4 = 1048576
constexpr size_t OF_CNT  = OF_HIST + 4ull*65536*4;    // 256
constexpr size_t OF_KTH  = OF_CNT + 256;              // 256
constexpr size_t OF_KEYS = OF_KTH + 256;              // 4*70400*4 = 1126400
constexpr size_t OF_CAND = OF_KEYS + 1126400;         // 4*2048*8 = 65536
constexpr size_t OF_TBOX = OF_CAND + 65536;           // 4*1024*7*4 = 114688
constexpr size_t OF_TSC  = OF_TBOX + 114688;          // 16384
constexpr size_t OF_BX1  = OF_TSC + 16384;
constexpr size_t OF_BX2  = OF_BX1 + 16384;
constexpr size_t OF_BY1  = OF_BX2 + 16384;
constexpr size_t OF_BY2  = OF_BY1 + 16384;
constexpr size_t OF_BAR  = OF_BY2 + 16384;
constexpr size_t OF_MASK = OF_BAR + 16384;            // 4*1024*32*4 = 524288
constexpr size_t OF_ROIS = OF_MASK + 524288;          // 4*512*7*4 = 57344
constexpr size_t OF_RSC  = OF_ROIS + 57344;           // 8192
constexpr size_t OF_BSW  = OF_RSC + 8192;             // 432*32768 = 14155776
constexpr size_t OF_WT   = OF_BSW + 14155776;         // 5*65536*4 = 1310720
constexpr size_t OF_PART = OF_WT + 1310720;           // 16*2048*256*4 = 33554432
constexpr size_t OF_X1   = OF_PART + 33554432;        // 2048*256*4 = 2097152
constexpr size_t OF_X2   = OF_X1 + 2097152;
constexpr size_t OF_C1   = OF_X2 + 2097152;
constexpr size_t OF_R1   = OF_C1 + 2097152;
constexpr size_t OF_C2   = OF_R1 + 2097152;
constexpr size_t OF_R2   = OF_C2 + 2097152;
constexpr size_t WS_NEED = OF_R2 + 2097152;

// ---------------- helpers ----------------
__device__ __forceinline__ u32 keyOf(float f) {
  u32 u = __float_as_uint(f);
  return (u & 0x80000000u) ? ~u : (u | 0x80000000u);
}
__device__ __forceinline__ float keyToF(u32 k) {
  u32 u = (k & 0x80000000u) ? (k ^ 0x80000000u) : ~k;
  return __uint_as_float(u);
}
__device__ __forceinline__ u16 f2bf(float f) {   // RNE f32 -> bf16
  u32 u = __float_as_uint(f);
  u32 r = 0x7FFFu + ((u >> 16) & 1u);
  return (u16)((u + r) >> 16);
}
__device__ __forceinline__ void gload_lds16(const void* g, void* l) {
  auto gp = reinterpret_cast<const __attribute__((address_space(1))) unsigned int*>(
      reinterpret_cast<uintptr_t>(g));
  auto lp = reinterpret_cast<__attribute__((address_space(3))) unsigned int*>(
      reinterpret_cast<uintptr_t>(l));
  __builtin_amdgcn_global_load_lds(gp, lp, 16, 0, 0);
}

// ---------------- zero hist + cnt (replaces pathological rocclr fill) ----------------
__global__ __launch_bounds__(256) void k_zero(u32* __restrict__ hist, u32* __restrict__ cnt)
{
  u32 i = blockIdx.x * 256u + threadIdx.x;          // 65536 threads
  ((u32x4*)hist)[i] = (u32x4){0u, 0u, 0u, 0u};      // 65536*16B = 1 MB exactly
  if (blockIdx.x == 0 && threadIdx.x < 64) cnt[threadIdx.x] = 0u;
}

// ---------------- weight prep: Ws1 -> swizzled bf16 tiles; small W transposes ----------------
__global__ __launch_bounds__(256) void k_prep(const float* __restrict__ Ws1,
    const float* __restrict__ W0, const float* __restrict__ W1, const float* __restrict__ W2,
    const float* __restrict__ W3, const float* __restrict__ W4,
    u32* __restrict__ Bsw, float* __restrict__ Wt)
{
  int bid = blockIdx.x, tid = threadIdx.x;
  if (bid < 13824) {
    u32 g = (u32)bid * 256u + tid;     // u32 index into Bsw (3538944 total)
    u32 tile = g >> 13;                // /8192 u32 per 32KB tile
    u32 rem = g & 8191u;
    u32 n = rem >> 5;                  // row 0..255
    u32 p = (rem & 31u) << 2;          // byte pos in row 0..124
    u32 q = p ^ ((n & 7u) << 4);       // inverse-swizzled logical byte
    u32 col = tile * 64u + (q >> 1);
    const float* src = Ws1 + (size_t)n * FEAT + col;
    Bsw[g] = (u32)f2bf(src[0]) | ((u32)f2bf(src[1]) << 16);
  } else {
    int mb = bid - 13824;              // 0..1279
    int mat = mb >> 8;
    int o = ((mb & 255) << 8) | tid;   // 0..65535 ; o = k*256+n
    int kk = o >> 8, n = o & 255;
    const float* W = (mat == 0) ? W0 : (mat == 1) ? W1 : (mat == 2) ? W2 : (mat == 3) ? W3 : W4;
    Wt[(size_t)mat * 65536 + o] = W[n * 256 + kk];
  }
}

// ---------------- scores -> sortable keys + hi16 histogram ----------------
__global__ __launch_bounds__(256) void k_keys(const float* __restrict__ cls,
    u32* __restrict__ keys, u32* __restrict__ hist)
{
  u32 g = blockIdx.x * 256u + threadIdx.x;
  if (g >= BATCH * A_CNT) return;
  u32 b = g / A_CNT;
  float s0 = cls[(size_t)g * 3 + 0];
  float s1 = cls[(size_t)g * 3 + 1];
  float s2 = cls[(size_t)g * 3 + 2];
  u32 k = keyOf(fmaxf(s0, fmaxf(s1, s2)));
  keys[g] = k;
  atomicAdd(&hist[b * 65536u + (k >> 16)], 1u);
}

// ---------------- find hi16 threshold of the 1024th largest ----------------
__global__ __launch_bounds__(256) void k_scan(const u32* __restrict__ hist, u32* __restrict__ kth)
{
  int b = blockIdx.x, t = threadIdx.x;
  const u32* H = hist + (size_t)b * 65536;
  __shared__ u32 buf[256];
  __shared__ u32 segsuf[256];
  __shared__ int sel;
  u32 s = 0;
  for (int j = 0; j < 256; ++j) s += H[t * 256 + j];
  buf[t] = s;
  __syncthreads();
  for (int d = 1; d < 256; d <<= 1) {
    u32 v = (t + d < 256) ? buf[t + d] : 0u;
    __syncthreads();
    buf[t] += v;
    __syncthreads();
  }
  segsuf[t] = buf[t];
  __syncthreads();
  if (buf[t] >= 1024u && (t == 255 || buf[t + 1] < 1024u)) sel = t;
  __syncthreads();
  int sg = sel;
  u32 above = (sg == 255) ? 0u : segsuf[sg + 1];
  u32 bc = H[sg * 256 + t];
  __syncthreads();
  buf[t] = bc;
  __syncthreads();
  for (int d = 1; d < 256; d <<= 1) {
    u32 v = (t + d < 256) ? buf[t + d] : 0u;
    __syncthreads();
    buf[t] += v;
    __syncthreads();
  }
  u32 self = above + buf[t];
  u32 nxt = above + ((t == 255) ? 0u : buf[t + 1]);
  if (self >= 1024u && (t == 255 || nxt < 1024u)) kth[b] = (u32)(sg * 256 + t);
}

// ---------------- compact candidates (hi16 >= threshold) ----------------
__global__ __launch_bounds__(256) void k_compact(const u32* __restrict__ keys,
    const u32* __restrict__ kth, u32* __restrict__ cnt, u64* __restrict__ cand)
{
  u32 g = blockIdx.x * 256u + threadIdx.x;
  if (g >= BATCH * A_CNT) return;
  u32 b = g / A_CNT;
  u32 k = keys[g];
  if ((k >> 16) >= kth[b]) {
    u32 pos = atomicAdd(&cnt[b], 1u);
    if (pos < 2048) {
      u32 a = g - b * A_CNT;
      cand[(size_t)b * 2048 + pos] = ((u64)k << 32) | (u32)(~a);
    }
  }
}

// ---------------- bitonic sort 2048 desc; emit sorted top-1024 + NMS geometry ----------------
__global__ __launch_bounds__(1024) void k_sort(const u64* __restrict__ cand, const u32* __restrict__ cnt,
    const float* __restrict__ boxes, float* __restrict__ tbox, float* __restrict__ tsc,
    float* __restrict__ bx1, float* __restrict__ bx2, float* __restrict__ by1,
    float* __restrict__ by2, float* __restrict__ bar)
{
  int b = blockIdx.x, t = threadIdx.x;
  __shared__ u64 s[2048];
  u32 m = cnt[b]; if (m > 2048u) m = 2048u;
  for (int e = t; e < 2048; e += 1024) s[e] = (e < (int)m) ? cand[(size_t)b * 2048 + e] : 0ull;
  __syncthreads();
  for (u32 k = 2; k <= 2048; k <<= 1) {
    for (u32 j = k >> 1; j > 0; j >>= 1) {
      for (int e = t; e < 2048; e += 1024) {
        u32 p = (u32)e ^ j;
        if (p > (u32)e) {
          bool desc = ((e & k) == 0);
          u64 x = s[e], y = s[p];
          if (desc ? (x < y) : (x > y)) { s[e] = y; s[p] = x; }
        }
      }
      __syncthreads();
    }
  }
  u64 comp = s[t];
  u32 kk = (u32)(comp >> 32);
  u32 a = ~(u32)(comp & 0xFFFFFFFFull);
  int o = b * 1024 + t;
  tsc[o] = keyToF(kk);
  const float* bp = boxes + ((size_t)b * A_CNT + a) * 7;
  float x = bp[0], y = bp[1], z = bp[2], dx = bp[3], dy = bp[4], dz = bp[5], rr = bp[6];
  float* tb = tbox + (size_t)o * 7;
  tb[0] = x; tb[1] = y; tb[2] = z; tb[3] = dx; tb[4] = dy; tb[5] = dz; tb[6] = rr;
  {
#pragma clang fp contract(off)
    bx1[o] = x - 0.5f * dx; bx2[o] = x + 0.5f * dx;
    by1[o] = y - 0.5f * dy; by2[o] = y + 0.5f * dy;
    bar[o] = dx * dy;
  }
}

// ---------------- NMS suppression bitmasks ----------------
__global__ __launch_bounds__(64) void k_mask(const float* __restrict__ bx1, const float* __restrict__ bx2,
    const float* __restrict__ by1, const float* __restrict__ by2, const float* __restrict__ bar,
    u32* __restrict__ mask)
{
  int cb = blockIdx.x, rb = blockIdx.y, b = blockIdx.z;
  int t = threadIdx.x;
  int r = rb * 64 + t;
  int o = b * 1024;
  __shared__ float cx1[64], cx2[64], cy1[64], cy2[64], car[64];
  int jc0 = cb * 64;
  cx1[t] = bx1[o + jc0 + t]; cx2[t] = bx2[o + jc0 + t];
  cy1[t] = by1[o + jc0 + t]; cy2[t] = by2[o + jc0 + t];
  car[t] = bar[o + jc0 + t];
  __syncthreads();
  float rx1 = bx1[o + r], rx2 = bx2[o + r], ry1 = by1[o + r], ry2 = by2[o + r], rar = bar[o + r];
  u32 w0 = 0, w1 = 0;
  {
#pragma clang fp contract(off)
    for (int c = 0; c < 64; ++c) {
      int jc = jc0 + c;
      float iw = fminf(rx2, cx2[c]) - fmaxf(rx1, cx1[c]); iw = fmaxf(iw, 0.0f);
      float ih = fminf(ry2, cy2[c]) - fmaxf(ry1, cy1[c]); ih = fmaxf(ih, 0.0f);
      float inter = iw * ih;
      float den = fmaxf(rar + car[c] - inter, 1e-6f);
      float iou = inter / den;
      if ((iou > 0.7f) && (jc > r)) {
        if (c < 32) w0 |= 1u << c; else w1 |= 1u << (c - 32);
      }
    }
  }
  mask[((size_t)(o + r)) * 32 + cb * 2 + 0] = w0;
  mask[((size_t)(o + r)) * 32 + cb * 2 + 1] = w1;
}

// ---------------- chunked sequential greedy NMS + compact to rois ----------------
__global__ __launch_bounds__(64) void k_nms(const u32* __restrict__ mask,
    const float* __restrict__ tbox, const float* __restrict__ tsc,
    float* __restrict__ rois, float* __restrict__ rsc)
{
  int b = blockIdx.x;
  int lane = threadIdx.x;
  int el = lane & 31;
  const u32* M = mask + (size_t)b * 1024 * 32;
  u32 R = 0;
  u32 cur[32], nxt[32];
#pragma unroll
  for (int i = 0; i < 32; ++i) cur[i] = M[(size_t)(i * 32 + el)];
#pragma unroll 1
  for (int c = 0; c < 32; ++c) {
    if (c < 31) {
      int nb = (c + 1) * 1024 + el;
#pragma unroll
      for (int i = 0; i < 32; ++i) nxt[i] = M[(size_t)(nb + i * 32)];
    }
    u32 w = R;
#pragma unroll
    for (int i = 0; i < 32; ++i) w |= ((w >> i) & 1u) ? 0u : cur[i];
    u32 wfin = __shfl(w, c, 64);
#pragma unroll
    for (int i = 0; i < 32; ++i) R |= ((wfin >> i) & 1u) ? 0u : cur[i];
#pragma unroll
    for (int i = 0; i < 32; ++i) cur[i] = nxt[i];
  }
  u32 keepw = (lane < 32) ? ~R : 0u;
  int c = __popc(keepw);
  int pre = c;
  for (int d = 1; d < 64; d <<= 1) {
    int v = __shfl_up(pre, d, 64);
    if (lane >= d) pre += v;
  }
  int total = __shfl(pre, 31, 64);
  int base = pre - c;
  if (lane < 32) {
    u32 w = keepw;
    int rank = base;
    while (w) {
      int bit = __ffs(w) - 1;
      w &= w - 1;
      if (rank < 512) {
        int r = lane * 32 + bit;
        const float* tb = tbox + ((size_t)b * 1024 + r) * 7;
        float* rp = rois + ((size_t)b * 512 + rank) * 7;
        rp[0] = tb[0]; rp[1] = tb[1]; rp[2] = tb[2]; rp[3] = tb[3];
        rp[4] = tb[4]; rp[5] = tb[5]; rp[6] = tb[6];
        rsc[b * 512 + rank] = tsc[b * 1024 + r];
      }
      rank++;
    }
  }
  for (int z = total + lane; z < 512; z += 64) {
    float* rp = rois + ((size_t)b * 512 + z) * 7;
    rp[0] = rp[1] = rp[2] = rp[3] = rp[4] = rp[5] = rp[6] = 0.0f;
    rsc[b * 512 + z] = 0.0f;
  }
}

// ---------------- GEMM1: (2048x27648 f32) @ Ws1^T -> split-K partials ----------------
__global__ __launch_bounds__(256) void k_gemm1(const float* __restrict__ A,
    const u32* __restrict__ Bsw, float* __restrict__ part)
{
  __shared__ u32x4 Alds4[64 * 8];    // 8 KB, swizzled bf16 image
  __shared__ u32x4 Blds4[256 * 8];   // 32 KB, swizzled bf16 image
  char* Alds = (char*)Alds4;
  char* Blds = (char*)Blds4;
  int bid = blockIdx.x;
  int mt = bid & 31, ks = bid >> 5;
  int tid = threadIdx.x, lane = tid & 63, wv = tid >> 6;

  f32x4 acc[4][4];
#pragma unroll
  for (int i = 0; i < 4; ++i)
#pragma unroll
    for (int j = 0; j < 4; ++j) acc[i][j] = (f32x4){0.f, 0.f, 0.f, 0.f};

  int am = tid >> 2;
  int ak = (tid & 3) * 16;                       // element offset in 64
  const float* ap_base = A + ((size_t)(mt * 64 + am)) * FEAT + (size_t)ks * KCHUNK + ak;
  int asw = (am & 7) << 4;
  int ac0 = (tid & 3) * 32;                      // byte chunk base
  char* aw0 = Alds + am * 128 + ((ac0) ^ asw);
  char* aw1 = Alds + am * 128 + ((ac0 + 16) ^ asw);
  const char* bsrc_base = (const char*)Bsw + ((size_t)(ks * NTILE_IT)) * 32768 + (wv * 8) * 1024 + lane * 16;
  char* bdst_base = Blds + (wv * 8) * 1024;

  int row16 = lane & 15, kgrp = lane >> 4;
  int aoff[4][2], boff[4][2];
#pragma unroll
  for (int ksub = 0; ksub < 2; ++ksub) {
    int q = ksub * 64 + kgrp * 16;
#pragma unroll
    for (int mf = 0; mf < 4; ++mf) {
      int row = mf * 16 + row16;
      aoff[mf][ksub] = row * 128 + (q ^ ((row & 7) << 4));
    }
#pragma unroll
    for (int nf = 0; nf < 4; ++nf) {
      int n = wv * 64 + nf * 16 + row16;
      boff[nf][ksub] = n * 128 + (q ^ ((n & 7) << 4));
    }
  }

  for (int it = 0; it < NTILE_IT; ++it) {
    // stage A (fp32 -> bf16, swizzled ds_write)
    const float4* ap = (const float4*)(ap_base + it * 64);
    float4 f0 = ap[0], f1 = ap[1], f2 = ap[2], f3 = ap[3];
    u32x4 c0, c1;
    c0.x = (u32)f2bf(f0.x) | ((u32)f2bf(f0.y) << 16);
    c0.y = (u32)f2bf(f0.z) | ((u32)f2bf(f0.w) << 16);
    c0.z = (u32)f2bf(f1.x) | ((u32)f2bf(f1.y) << 16);
    c0.w = (u32)f2bf(f1.z) | ((u32)f2bf(f1.w) << 16);
    c1.x = (u32)f2bf(f2.x) | ((u32)f2bf(f2.y) << 16);
    c1.y = (u32)f2bf(f2.z) | ((u32)f2bf(f2.w) << 16);
    c1.z = (u32)f2bf(f3.x) | ((u32)f2bf(f3.y) << 16);
    c1.w = (u32)f2bf(f3.z) | ((u32)f2bf(f3.w) << 16);
    *(u32x4*)aw0 = c0;
    *(u32x4*)aw1 = c1;
    // stage B (pre-swizzled source -> linear LDS)
    const char* bs = bsrc_base + (size_t)it * 32768;
#pragma unroll
    for (int i = 0; i < 8; ++i) gload_lds16(bs + i * 1024, bdst_base + i * 1024);
    __syncthreads();
    // compute
    bf16x8 af[4][2], bfv[4][2];
#pragma unroll
    for (int ksub = 0; ksub < 2; ++ksub) {
#pragma unroll
      for (int mf = 0; mf < 4; ++mf) af[mf][ksub] = *(const bf16x8*)(Alds + aoff[mf][ksub]);
#pragma unroll
      for (int nf = 0; nf < 4; ++nf) bfv[nf][ksub] = *(const bf16x8*)(Blds + boff[nf][ksub]);
    }
#pragma unroll
    for (int ksub = 0; ksub < 2; ++ksub)
#pragma unroll
      for (int mf = 0; mf < 4; ++mf)
#pragma unroll
        for (int nf = 0; nf < 4; ++nf)
          acc[mf][nf] = __builtin_amdgcn_mfma_f32_16x16x32_bf16(af[mf][ksub], bfv[nf][ksub], acc[mf][nf], 0, 0, 0);
    __syncthreads();
  }
  // epilogue: write split-K partial
  float* pb = part + (size_t)ks * 524288;
#pragma unroll
  for (int mf = 0; mf < 4; ++mf) {
    int row = mt * 64 + mf * 16 + kgrp * 4;
#pragma unroll
    for (int nf = 0; nf < 4; ++nf) {
      int col = wv * 64 + nf * 16 + row16;
#pragma unroll
      for (int rr = 0; rr < 4; ++rr)
        pb[(size_t)(row + rr) * 256 + col] = acc[mf][nf][rr];
    }
  }
}

// ---------------- reduce split-K partials + BN+ReLU ----------------
__global__ __launch_bounds__(256) void k_reduce1(const float* __restrict__ part,
    const float* __restrict__ g, const float* __restrict__ bb, float* __restrict__ x)
{
  int i = blockIdx.x * 256 + threadIdx.x;   // < 524288
  float s = 0.f;
#pragma unroll
  for (int ks = 0; ks < KSPLIT; ++ks) s += part[(size_t)ks * 524288 + i];
  int n = i & 255;
  float sc = g[n] / sqrtf(1.0f + 1e-5f);
  x[i] = fmaxf(fmaf(s, sc, bb[n]), 0.0f);
}

// ---------------- small fp32 GEMM 2048x256x256 + BN+ReLU ----------------
__global__ __launch_bounds__(256) void k_small(const float* __restrict__ X, const float* __restrict__ WT,
    const float* __restrict__ g, const float* __restrict__ bb, float* __restrict__ Y)
{
  __shared__ __align__(16) float xs[8][256];
  int bid = blockIdx.x, t = threadIdx.x;
#pragma unroll
  for (int r = 0; r < 8; ++r) xs[r][t] = X[(size_t)(bid * 8 + r) * 256 + t];
  __syncthreads();
  float acc[8] = {0, 0, 0, 0, 0, 0, 0, 0};
  for (int k = 0; k < 256; k += 4) {
    float w0 = WT[(k + 0) * 256 + t];
    float w1 = WT[(k + 1) * 256 + t];
    float w2 = WT[(k + 2) * 256 + t];
    float w3 = WT[(k + 3) * 256 + t];
#pragma unroll
    for (int r = 0; r < 8; ++r) {
      float4 xv = *(const float4*)&xs[r][k];
      acc[r] = fmaf(xv.x, w0, acc[r]);
      acc[r] = fmaf(xv.y, w1, acc[r]);
      acc[r] = fmaf(xv.z, w2, acc[r]);
      acc[r] = fmaf(xv.w, w3, acc[r]);
    }
  }
  float sc = g[t] / sqrtf(1.0f + 1e-5f);
  float bv = bb[t];
#pragma unroll
  for (int r = 0; r < 8; ++r)
    Y[(size_t)(bid * 8 + r) * 256 + t] = fmaxf(fmaf(acc[r], sc, bv), 0.0f);
}

// ---------------- final heads + box decode + output assembly ----------------
__global__ __launch_bounds__(256) void k_final(const float* __restrict__ c2, const float* __restrict__ r2,
    const float* __restrict__ Wc3, const float* __restrict__ bc3,
    const float* __restrict__ Wr3, const float* __restrict__ br3,
    const float* __restrict__ rois, const float* __restrict__ rsc, float* __restrict__ out)
{
  int m = blockIdx.x * 4 + (threadIdx.x >> 6);
  int lane = threadIdx.x & 63;
  float4 cv = ((const float4*)(c2 + (size_t)m * 256))[lane];
  float4 rv = ((const float4*)(r2 + (size_t)m * 256))[lane];
  float4 wc = ((const float4*)Wc3)[lane];
  float pc = cv.x * wc.x + cv.y * wc.y + cv.z * wc.z + cv.w * wc.w;
#pragma unroll
  for (int off = 32; off > 0; off >>= 1) pc += __shfl_xor(pc, off, 64);
  float rg[7];
#pragma unroll
  for (int j = 0; j < 7; ++j) {
    float4 wr = ((const float4*)(Wr3 + j * 256))[lane];
    float p = rv.x * wr.x + rv.y * wr.y + rv.z * wr.z + rv.w * wr.w;
#pragma unroll
    for (int off = 32; off > 0; off >>= 1) p += __shfl_xor(p, off, 64);
    rg[j] = p + br3[j];
  }
  if (lane == 0) {
    float cls = pc + bc3[0];
    const float* R = rois + (size_t)m * 7;
    float rx = R[0], ry = R[1], rz = R[2], dxa = R[3], dya = R[4], dza = R[5], ra = R[6];
    float diag = sqrtf(dxa * dxa + dya * dya);
    float x = rg[0] * diag, y = rg[1] * diag, z = rg[2] * dza;
    float ex = expf(rg[3]) * dxa, ey = expf(rg[4]) * dya, ez = expf(rg[5]) * dza;
    float hr = rg[6] + ra;
    float cc = cosf(ra), sn = sinf(ra);
    float xr = x * cc - y * sn, yr = x * sn + y * cc;
    float* O = out + (size_t)m * 9;
    O[0] = cls; O[1] = xr + rx; O[2] = yr + ry; O[3] = z + rz;
    O[4] = ex; O[5] = ey; O[6] = ez; O[7] = hr; O[8] = rsc[m];
  }
}

// ---------------- launch ----------------
extern "C" void kernel_launch(void* const* d_in, const int* in_sizes, int n_in,
                              void* d_out, int out_size, void* d_ws, size_t ws_size,
                              hipStream_t stream)
{
  const float* rpn_box = (const float*)d_in[0];
  const float* rpn_cls = (const float*)d_in[1];
  const float* pooled  = (const float*)d_in[2];
  const float* Ws1 = (const float*)d_in[3];
  const float* g1  = (const float*)d_in[4];
  const float* b1  = (const float*)d_in[5];
  const float* Ws2 = (const float*)d_in[6];
  const float* g2  = (const float*)d_in[7];
  const float* b2  = (const float*)d_in[8];
  const float* Wc1 = (const float*)d_in[9];
  const float* gc1 = (const float*)d_in[10];
  const float* bc1 = (const float*)d_in[11];
  const float* Wc2 = (const float*)d_in[12];
  const float* gc2 = (const float*)d_in[13];
  const float* bc2 = (const float*)d_in[14];
  const float* Wc3 = (const float*)d_in[15];
  const float* bc3 = (const float*)d_in[16];
  const float* Wr1 = (const float*)d_in[17];
  const float* gr1 = (const float*)d_in[18];
  const float* br1 = (const float*)d_in[19];
  const float* Wr2 = (const float*)d_in[20];
  const float* gr2 = (const float*)d_in[21];
  const float* br2 = (const float*)d_in[22];
  const float* Wr3 = (const float*)d_in[23];
  const float* br3 = (const float*)d_in[24];

  if (ws_size < WS_NEED) return;  // workspace insufficient (would need fallback)

  char* ws = (char*)d_ws;
  u32* hist = (u32*)(ws + OF_HIST);
  u32* cnt  = (u32*)(ws + OF_CNT);
  u32* kth  = (u32*)(ws + OF_KTH);
  u32* keys = (u32*)(ws + OF_KEYS);
  u64* cand = (u64*)(ws + OF_CAND);
  float* tbox = (float*)(ws + OF_TBOX);
  float* tsc  = (float*)(ws + OF_TSC);
  float* bx1 = (float*)(ws + OF_BX1);
  float* bx2 = (float*)(ws + OF_BX2);
  float* by1 = (float*)(ws + OF_BY1);
  float* by2 = (float*)(ws + OF_BY2);
  float* bar = (float*)(ws + OF_BAR);
  u32* mask = (u32*)(ws + OF_MASK);
  float* roisb = (float*)(ws + OF_ROIS);
  float* rscb  = (float*)(ws + OF_RSC);
  u32* Bsw = (u32*)(ws + OF_BSW);
  float* Wt = (float*)(ws + OF_WT);
  float* part = (float*)(ws + OF_PART);
  float* x1 = (float*)(ws + OF_X1);
  float* x2 = (float*)(ws + OF_X2);
  float* c1 = (float*)(ws + OF_C1);
  float* r1 = (float*)(ws + OF_R1);
  float* c2 = (float*)(ws + OF_C2);
  float* r2 = (float*)(ws + OF_R2);

  k_zero<<<256, 256, 0, stream>>>(hist, cnt);
  k_prep<<<15104, 256, 0, stream>>>(Ws1, Ws2, Wc1, Wc2, Wr1, Wr2, Bsw, Wt);
  k_keys<<<1100, 256, 0, stream>>>(rpn_cls, keys, hist);
  k_scan<<<4, 256, 0, stream>>>(hist, kth);
  k_compact<<<1100, 256, 0, stream>>>(keys, kth, cnt, cand);
  k_sort<<<4, 1024, 0, stream>>>(cand, cnt, rpn_box, tbox, tsc, bx1, bx2, by1, by2, bar);
  k_mask<<<dim3(16, 16, 4), 64, 0, stream>>>(bx1, bx2, by1, by2, bar, mask);
  k_nms<<<4, 64, 0, stream>>>(mask, tbox, tsc, roisb, rscb);

  k_gemm1<<<512, 256, 0, stream>>>(pooled, Bsw, part);
  k_reduce1<<<2048, 256, 0, stream>>>(part, g1, b1, x1);
  k_small<<<256, 256, 0, stream>>>(x1, Wt + 0 * 65536, g2, b2, x2);
  k_small<<<256, 256, 0, stream>>>(x2, Wt + 1 * 65536, gc1, bc1, c1);
  k_small<<<256, 256, 0, stream>>>(x2, Wt + 3 * 65536, gr1, br1, r1);
  k_small<<<256, 256, 0, stream>>>(c1, Wt + 2 * 65536, gc2, bc2, c2);
  k_small<<<256, 256, 0, stream>>>(r1, Wt + 4 * 65536, gr2, br2, r2);
  k_final<<<512, 256, 0, stream>>>(c2, r2, Wc3, bc3, Wr3, br3, roisb, rscb, (float*)d_out);
}

// Round 4
// 320.280 us; speedup vs baseline: 1.5332x; 1.1663x over previous
//
#include <hip/hip_runtime.h>
#include <cstdint>

typedef unsigned int u32;
typedef unsigned long long u64;
typedef unsigned short u16;

#define BATCH 4
#define A_CNT 70400
#define FEAT 27648
#define KSPLIT 16
#define KCHUNK 1728          // FEAT/KSPLIT
#define NTILE_IT 27          // KCHUNK/64

typedef __attribute__((ext_vector_type(8))) short bf16x8;
typedef __attribute__((ext_vector_type(4))) float f32x4;
typedef __attribute__((ext_vector_type(4))) u32 u32x4;

// ---------------- workspace layout ----------------
constexpr size_t OF_KEYS = 0;                         // 4*70400*4 = 1126400
constexpr size_t OF_TBOX = OF_KEYS + 1126400;         // 4*1024*7*4 = 114688
constexpr size_t OF_TSC  = OF_TBOX + 114688;          // 16384
constexpr size_t OF_BX1  = OF_TSC + 16384;
constexpr size_t OF_BX2  = OF_BX1 + 16384;
constexpr size_t OF_BY1  = OF_BX2 + 16384;
constexpr size_t OF_BY2  = OF_BY1 + 16384;
constexpr size_t OF_BAR  = OF_BY2 + 16384;
constexpr size_t OF_MASK = OF_BAR + 16384;            // 4*1024*32*4 = 524288
constexpr size_t OF_ROIS = OF_MASK + 524288;          // 4*512*7*4 = 57344
constexpr size_t OF_RSC  = OF_ROIS + 57344;           // 8192
constexpr size_t OF_BSW  = OF_RSC + 8192;             // 432*32768 = 14155776
constexpr size_t OF_WT   = OF_BSW + 14155776;         // 5*65536*4 = 1310720
constexpr size_t OF_PART = OF_WT + 1310720;           // 16*2048*256*4 = 33554432
constexpr size_t WS_NEED = OF_PART + 33554432;

// ---------------- helpers ----------------
__device__ __forceinline__ u32 keyOf(float f) {
  u32 u = __float_as_uint(f);
  return (u & 0x80000000u) ? ~u : (u | 0x80000000u);
}
__device__ __forceinline__ float keyToF(u32 k) {
  u32 u = (k & 0x80000000u) ? (k ^ 0x80000000u) : ~k;
  return __uint_as_float(u);
}
__device__ __forceinline__ u16 f2bf(float f) {   // RNE f32 -> bf16
  u32 u = __float_as_uint(f);
  u32 r = 0x7FFFu + ((u >> 16) & 1u);
  return (u16)((u + r) >> 16);
}
__device__ __forceinline__ void gload_lds16(const void* g, void* l) {
  auto gp = reinterpret_cast<const __attribute__((address_space(1))) unsigned int*>(
      reinterpret_cast<uintptr_t>(g));
  auto lp = reinterpret_cast<__attribute__((address_space(3))) unsigned int*>(
      reinterpret_cast<uintptr_t>(l));
  __builtin_amdgcn_global_load_lds(gp, lp, 16, 0, 0);
}

// ---------------- weight prep: Ws1 -> swizzled bf16 tiles; small W transposes ----------------
__global__ __launch_bounds__(256) void k_prep(const float* __restrict__ Ws1,
    const float* __restrict__ W0, const float* __restrict__ W1, const float* __restrict__ W2,
    const float* __restrict__ W3, const float* __restrict__ W4,
    u32* __restrict__ Bsw, float* __restrict__ Wt)
{
  int bid = blockIdx.x, tid = threadIdx.x;
  if (bid < 3456) {
    u32 w = (u32)bid * 256u + tid;     // u32x4 index (884736 total)
    u32 tile = w >> 11;                // 2048 u32x4 per 32KB tile
    u32 rem = w & 2047u;
    u32 n = rem >> 3;                  // row 0..255
    u32 pq = (rem & 7u) << 4;          // 16B-aligned byte pos in row
    u32 q0 = pq ^ ((n & 7u) << 4);     // inverse-swizzled logical byte (16B aligned)
    u32 col0 = tile * 64u + (q0 >> 1);
    const float* src = Ws1 + (size_t)n * FEAT + col0;
    float4 f0 = *(const float4*)src;
    float4 f1 = *(const float4*)(src + 4);
    u32x4 o;
    o.x = (u32)f2bf(f0.x) | ((u32)f2bf(f0.y) << 16);
    o.y = (u32)f2bf(f0.z) | ((u32)f2bf(f0.w) << 16);
    o.z = (u32)f2bf(f1.x) | ((u32)f2bf(f1.y) << 16);
    o.w = (u32)f2bf(f1.z) | ((u32)f2bf(f1.w) << 16);
    ((u32x4*)Bsw)[w] = o;
  } else {
    int mb = bid - 3456;               // 0..1279
    int mat = mb >> 8;
    int o = ((mb & 255) << 8) | tid;   // 0..65535 ; o = k*256+n
    int kk = o >> 8, n = o & 255;
    const float* W = (mat == 0) ? W0 : (mat == 1) ? W1 : (mat == 2) ? W2 : (mat == 3) ? W3 : W4;
    Wt[(size_t)mat * 65536 + o] = W[n * 256 + kk];
  }
}

// ---------------- fused proposal: keys + 2-level LDS histogram threshold +
//                  compact + bitonic sort + NMS geometry ----------------
__global__ __launch_bounds__(1024) void k_prop(const float* __restrict__ cls,
    const float* __restrict__ boxes, u32* __restrict__ keys,
    float* __restrict__ tbox, float* __restrict__ tsc,
    float* __restrict__ bx1, float* __restrict__ bx2, float* __restrict__ by1,
    float* __restrict__ by2, float* __restrict__ bar)
{
  int b = blockIdx.x, t = threadIdx.x;
  __shared__ u64 s[2048];
  __shared__ u32 h8[256], buf[256];
  __shared__ u32 sh_above, cc;
  __shared__ int selb, selk;
  const float* cb = cls + (size_t)b * A_CNT * 3;
  u32* kb = keys + (size_t)b * A_CNT;

  // phase A: keys + hi-8 histogram
  if (t < 256) h8[t] = 0u;
  __syncthreads();
  for (int g = t; g < A_CNT; g += 1024) {
    float s0 = cb[(size_t)g * 3 + 0];
    float s1 = cb[(size_t)g * 3 + 1];
    float s2 = cb[(size_t)g * 3 + 2];
    u32 k = keyOf(fmaxf(s0, fmaxf(s1, s2)));
    kb[g] = k;
    atomicAdd(&h8[k >> 24], 1u);
  }
  __syncthreads();
  // suffix scan (Hillis-Steele) of h8 -> buf
  if (t < 256) buf[t] = h8[t];
  __syncthreads();
  for (int d = 1; d < 256; d <<= 1) {
    u32 v = (t < 256 && t + d < 256) ? buf[t + d] : 0u;
    __syncthreads();
    if (t < 256) buf[t] += v;
    __syncthreads();
  }
  if (t < 256 && buf[t] >= 1024u && (t == 255 || buf[t + 1] < 1024u)) selb = t;
  __syncthreads();
  int b8 = selb;
  if (t == 0) sh_above = (b8 == 255) ? 0u : buf[b8 + 1];
  if (t < 256) h8[t] = 0u;
  __syncthreads();
  // phase B: lo-8 histogram within selected hi-8 bin
  for (int g = t; g < A_CNT; g += 1024) {
    u32 k = kb[g];
    if ((int)(k >> 24) == b8) atomicAdd(&h8[(k >> 16) & 255u], 1u);
  }
  __syncthreads();
  if (t < 256) buf[t] = h8[t];
  __syncthreads();
  for (int d = 1; d < 256; d <<= 1) {
    u32 v = (t < 256 && t + d < 256) ? buf[t + d] : 0u;
    __syncthreads();
    if (t < 256) buf[t] += v;
    __syncthreads();
  }
  u32 above = sh_above;
  if (t < 256 && above + buf[t] >= 1024u &&
      (t == 255 || above + buf[t + 1] < 1024u)) selk = t;
  if (t == 0) cc = 0u;
  __syncthreads();
  u32 kth = ((u32)b8 << 8) | (u32)selk;
  // phase C: compact candidates into LDS
  for (int g = t; g < A_CNT; g += 1024) {
    u32 k = kb[g];
    if ((k >> 16) >= kth) {
      u32 pos = atomicAdd(&cc, 1u);
      if (pos < 2048u) s[pos] = ((u64)k << 32) | (u32)(~(u32)g);
    }
  }
  __syncthreads();
  u32 m = cc; if (m > 2048u) m = 2048u;
  for (int e = t; e < 2048; e += 1024) if (e >= (int)m) s[e] = 0ull;
  __syncthreads();
  // phase D: bitonic sort 2048 desc
  for (u32 k = 2; k <= 2048; k <<= 1) {
    for (u32 j = k >> 1; j > 0; j >>= 1) {
      for (int e = t; e < 2048; e += 1024) {
        u32 p = (u32)e ^ j;
        if (p > (u32)e) {
          bool desc = ((e & k) == 0);
          u64 x = s[e], y = s[p];
          if (desc ? (x < y) : (x > y)) { s[e] = y; s[p] = x; }
        }
      }
      __syncthreads();
    }
  }
  // phase E: geometry tail
  u64 comp = s[t];
  u32 kk = (u32)(comp >> 32);
  u32 a = ~(u32)(comp & 0xFFFFFFFFull);
  int o = b * 1024 + t;
  tsc[o] = keyToF(kk);
  const float* bp = boxes + ((size_t)b * A_CNT + a) * 7;
  float x = bp[0], y = bp[1], z = bp[2], dx = bp[3], dy = bp[4], dz = bp[5], rr = bp[6];
  float* tb = tbox + (size_t)o * 7;
  tb[0] = x; tb[1] = y; tb[2] = z; tb[3] = dx; tb[4] = dy; tb[5] = dz; tb[6] = rr;
  {
#pragma clang fp contract(off)
    bx1[o] = x - 0.5f * dx; bx2[o] = x + 0.5f * dx;
    by1[o] = y - 0.5f * dy; by2[o] = y + 0.5f * dy;
    bar[o] = dx * dy;
  }
}

// ---------------- NMS suppression bitmasks ----------------
__global__ __launch_bounds__(64) void k_mask(const float* __restrict__ bx1, const float* __restrict__ bx2,
    const float* __restrict__ by1, const float* __restrict__ by2, const float* __restrict__ bar,
    u32* __restrict__ mask)
{
  int cb = blockIdx.x, rb = blockIdx.y, b = blockIdx.z;
  int t = threadIdx.x;
  int r = rb * 64 + t;
  int o = b * 1024;
  __shared__ float cx1[64], cx2[64], cy1[64], cy2[64], car[64];
  int jc0 = cb * 64;
  cx1[t] = bx1[o + jc0 + t]; cx2[t] = bx2[o + jc0 + t];
  cy1[t] = by1[o + jc0 + t]; cy2[t] = by2[o + jc0 + t];
  car[t] = bar[o + jc0 + t];
  __syncthreads();
  float rx1 = bx1[o + r], rx2 = bx2[o + r], ry1 = by1[o + r], ry2 = by2[o + r], rar = bar[o + r];
  u32 w0 = 0, w1 = 0;
  {
#pragma clang fp contract(off)
    for (int c = 0; c < 64; ++c) {
      int jc = jc0 + c;
      float iw = fminf(rx2, cx2[c]) - fmaxf(rx1, cx1[c]); iw = fmaxf(iw, 0.0f);
      float ih = fminf(ry2, cy2[c]) - fmaxf(ry1, cy1[c]); ih = fmaxf(ih, 0.0f);
      float inter = iw * ih;
      float den = fmaxf(rar + car[c] - inter, 1e-6f);
      float iou = inter / den;
      if ((iou > 0.7f) && (jc > r)) {
        if (c < 32) w0 |= 1u << c; else w1 |= 1u << (c - 32);
      }
    }
  }
  mask[((size_t)(o + r)) * 32 + cb * 2 + 0] = w0;
  mask[((size_t)(o + r)) * 32 + cb * 2 + 1] = w1;
}

// ---------------- chunked sequential greedy NMS + compact to rois ----------------
__global__ __launch_bounds__(64) void k_nms(const u32* __restrict__ mask,
    const float* __restrict__ tbox, const float* __restrict__ tsc,
    float* __restrict__ rois, float* __restrict__ rsc)
{
  int b = blockIdx.x;
  int lane = threadIdx.x;
  int el = lane & 31;
  const u32* M = mask + (size_t)b * 1024 * 32;
  u32 R = 0;
  u32 cur[32], nxt[32];
#pragma unroll
  for (int i = 0; i < 32; ++i) cur[i] = M[(size_t)(i * 32 + el)];
#pragma unroll 1
  for (int c = 0; c < 32; ++c) {
    if (c < 31) {
      int nb = (c + 1) * 1024 + el;
#pragma unroll
      for (int i = 0; i < 32; ++i) nxt[i] = M[(size_t)(nb + i * 32)];
    }
    u32 w = R;
#pragma unroll
    for (int i = 0; i < 32; ++i) w |= ((w >> i) & 1u) ? 0u : cur[i];
    u32 wfin = __shfl(w, c, 64);
#pragma unroll
    for (int i = 0; i < 32; ++i) R |= ((wfin >> i) & 1u) ? 0u : cur[i];
#pragma unroll
    for (int i = 0; i < 32; ++i) cur[i] = nxt[i];
  }
  u32 keepw = (lane < 32) ? ~R : 0u;
  int c = __popc(keepw);
  int pre = c;
  for (int d = 1; d < 64; d <<= 1) {
    int v = __shfl_up(pre, d, 64);
    if (lane >= d) pre += v;
  }
  int total = __shfl(pre, 31, 64);
  int base = pre - c;
  if (lane < 32) {
    u32 w = keepw;
    int rank = base;
    while (w) {
      int bit = __ffs(w) - 1;
      w &= w - 1;
      if (rank < 512) {
        int r = lane * 32 + bit;
        const float* tb = tbox + ((size_t)b * 1024 + r) * 7;
        float* rp = rois + ((size_t)b * 512 + rank) * 7;
        rp[0] = tb[0]; rp[1] = tb[1]; rp[2] = tb[2]; rp[3] = tb[3];
        rp[4] = tb[4]; rp[5] = tb[5]; rp[6] = tb[6];
        rsc[b * 512 + rank] = tsc[b * 1024 + r];
      }
      rank++;
    }
  }
  for (int z = total + lane; z < 512; z += 64) {
    float* rp = rois + ((size_t)b * 512 + z) * 7;
    rp[0] = rp[1] = rp[2] = rp[3] = rp[4] = rp[5] = rp[6] = 0.0f;
    rsc[b * 512 + z] = 0.0f;
  }
}

// ---------------- GEMM1: (2048x27648 f32) @ Ws1^T -> split-K partials ----------------
__global__ __launch_bounds__(256) void k_gemm1(const float* __restrict__ A,
    const u32* __restrict__ Bsw, float* __restrict__ part)
{
  __shared__ u32x4 Alds4[64 * 8];    // 8 KB, swizzled bf16 image
  __shared__ u32x4 Blds4[256 * 8];   // 32 KB, swizzled bf16 image
  char* Alds = (char*)Alds4;
  char* Blds = (char*)Blds4;
  int bid = blockIdx.x;
  int mt = bid & 31, ks = bid >> 5;
  int tid = threadIdx.x, lane = tid & 63, wv = tid >> 6;

  f32x4 acc[4][4];
#pragma unroll
  for (int i = 0; i < 4; ++i)
#pragma unroll
    for (int j = 0; j < 4; ++j) acc[i][j] = (f32x4){0.f, 0.f, 0.f, 0.f};

  int am = tid >> 2;
  int ak = (tid & 3) * 16;                       // element offset in 64
  const float* ap_base = A + ((size_t)(mt * 64 + am)) * FEAT + (size_t)ks * KCHUNK + ak;
  int asw = (am & 7) << 4;
  int ac0 = (tid & 3) * 32;                      // byte chunk base
  char* aw0 = Alds + am * 128 + ((ac0) ^ asw);
  char* aw1 = Alds + am * 128 + ((ac0 + 16) ^ asw);
  const char* bsrc_base = (const char*)Bsw + ((size_t)(ks * NTILE_IT)) * 32768 + (wv * 8) * 1024 + lane * 16;
  char* bdst_base = Blds + (wv * 8) * 1024;

  int row16 = lane & 15, kgrp = lane >> 4;
  int aoff[4][2], boff[4][2];
#pragma unroll
  for (int ksub = 0; ksub < 2; ++ksub) {
    int q = ksub * 64 + kgrp * 16;
#pragma unroll
    for (int mf = 0; mf < 4; ++mf) {
      int row = mf * 16 + row16;
      aoff[mf][ksub] = row * 128 + (q ^ ((row & 7) << 4));
    }
#pragma unroll
    for (int nf = 0; nf < 4; ++nf) {
      int n = wv * 64 + nf * 16 + row16;
      boff[nf][ksub] = n * 128 + (q ^ ((n & 7) << 4));
    }
  }

  for (int it = 0; it < NTILE_IT; ++it) {
    // stage A (fp32 -> bf16, swizzled ds_write)
    const float4* ap = (const float4*)(ap_base + it * 64);
    float4 f0 = ap[0], f1 = ap[1], f2 = ap[2], f3 = ap[3];
    u32x4 c0, c1;
    c0.x = (u32)f2bf(f0.x) | ((u32)f2bf(f0.y) << 16);
    c0.y = (u32)f2bf(f0.z) | ((u32)f2bf(f0.w) << 16);
    c0.z = (u32)f2bf(f1.x) | ((u32)f2bf(f1.y) << 16);
    c0.w = (u32)f2bf(f1.z) | ((u32)f2bf(f1.w) << 16);
    c1.x = (u32)f2bf(f2.x) | ((u32)f2bf(f2.y) << 16);
    c1.y = (u32)f2bf(f2.z) | ((u32)f2bf(f2.w) << 16);
    c1.z = (u32)f2bf(f3.x) | ((u32)f2bf(f3.y) << 16);
    c1.w = (u32)f2bf(f3.z) | ((u32)f2bf(f3.w) << 16);
    *(u32x4*)aw0 = c0;
    *(u32x4*)aw1 = c1;
    // stage B (pre-swizzled source -> linear LDS)
    const char* bs = bsrc_base + (size_t)it * 32768;
#pragma unroll
    for (int i = 0; i < 8; ++i) gload_lds16(bs + i * 1024, bdst_base + i * 1024);
    __syncthreads();
    // compute
    bf16x8 af[4][2], bfv[4][2];
#pragma unroll
    for (int ksub = 0; ksub < 2; ++ksub) {
#pragma unroll
      for (int mf = 0; mf < 4; ++mf) af[mf][ksub] = *(const bf16x8*)(Alds + aoff[mf][ksub]);
#pragma unroll
      for (int nf = 0; nf < 4; ++nf) bfv[nf][ksub] = *(const bf16x8*)(Blds + boff[nf][ksub]);
    }
#pragma unroll
    for (int ksub = 0; ksub < 2; ++ksub)
#pragma unroll
      for (int mf = 0; mf < 4; ++mf)
#pragma unroll
        for (int nf = 0; nf < 4; ++nf)
          acc[mf][nf] = __builtin_amdgcn_mfma_f32_16x16x32_bf16(af[mf][ksub], bfv[nf][ksub], acc[mf][nf], 0, 0, 0);
    __syncthreads();
  }
  // epilogue: write split-K partial
  float* pb = part + (size_t)ks * 524288;
#pragma unroll
  for (int mf = 0; mf < 4; ++mf) {
    int row = mt * 64 + mf * 16 + kgrp * 4;
#pragma unroll
    for (int nf = 0; nf < 4; ++nf) {
      int col = wv * 64 + nf * 16 + row16;
#pragma unroll
      for (int rr = 0; rr < 4; ++rr)
        pb[(size_t)(row + rr) * 256 + col] = acc[mf][nf][rr];
    }
  }
}

// ---------------- one 256x256 layer (8 rows/block) + BN + ReLU, LDS->LDS ----------------
__device__ __forceinline__ void layer8(const float (*IN)[256], const float* __restrict__ WT,
    const float* __restrict__ g, const float* __restrict__ bb, float (*OUT)[256], int t)
{
  float acc[8] = {0, 0, 0, 0, 0, 0, 0, 0};
  for (int k = 0; k < 256; k += 4) {
    float w0 = WT[(k + 0) * 256 + t];
    float w1 = WT[(k + 1) * 256 + t];
    float w2 = WT[(k + 2) * 256 + t];
    float w3 = WT[(k + 3) * 256 + t];
#pragma unroll
    for (int r = 0; r < 8; ++r) {
      float4 xv = *(const float4*)&IN[r][k];
      acc[r] = fmaf(xv.x, w0, acc[r]);
      acc[r] = fmaf(xv.y, w1, acc[r]);
      acc[r] = fmaf(xv.z, w2, acc[r]);
      acc[r] = fmaf(xv.w, w3, acc[r]);
    }
  }
  float sc = g[t] / sqrtf(1.0f + 1e-5f);
  float bv = bb[t];
#pragma unroll
  for (int r = 0; r < 8; ++r)
    OUT[r][t] = fmaxf(fmaf(acc[r], sc, bv), 0.0f);
}

// ---------------- fused head chain: reduce+x1 -> x2 -> {c1,r1} -> {c2,r2} -> heads+decode+out ----------------
__global__ __launch_bounds__(256) void k_chain(const float* __restrict__ part,
    const float* __restrict__ Wt,
    const float* __restrict__ g1, const float* __restrict__ b1,
    const float* __restrict__ g2, const float* __restrict__ b2,
    const float* __restrict__ gc1, const float* __restrict__ bc1,
    const float* __restrict__ gc2, const float* __restrict__ bc2,
    const float* __restrict__ gr1, const float* __restrict__ br1,
    const float* __restrict__ gr2, const float* __restrict__ br2,
    const float* __restrict__ Wc3, const float* __restrict__ bc3,
    const float* __restrict__ Wr3, const float* __restrict__ br3,
    const float* __restrict__ rois, const float* __restrict__ rsc,
    float* __restrict__ out)
{
  int bid = blockIdx.x, t = threadIdx.x;
  __shared__ __align__(16) float bufX[8][256];
  __shared__ __align__(16) float bufY[8][256];
  __shared__ __align__(16) float bufC[8][256];
  __shared__ __align__(16) float bufR[8][256];
  __shared__ float hd[64];
  // phase 0: x1 = BN_ReLU(sum_ks part)
  {
    float sc = g1[t] / sqrtf(1.0f + 1e-5f);
    float bv = b1[t];
#pragma unroll
    for (int r = 0; r < 8; ++r) {
      float s = 0.f;
#pragma unroll
      for (int ks = 0; ks < KSPLIT; ++ks)
        s += part[(size_t)ks * 524288 + (size_t)(bid * 8 + r) * 256 + t];
      bufX[r][t] = fmaxf(fmaf(s, sc, bv), 0.0f);
    }
  }
  __syncthreads();
  layer8(bufX, Wt + 0 * 65536, g2, b2, bufY, t);         // x2
  __syncthreads();
  layer8(bufY, Wt + 1 * 65536, gc1, bc1, bufC, t);       // c1
  layer8(bufY, Wt + 3 * 65536, gr1, br1, bufR, t);       // r1
  __syncthreads();
  layer8(bufC, Wt + 2 * 65536, gc2, bc2, bufX, t);       // c2 -> bufX
  layer8(bufR, Wt + 4 * 65536, gr2, br2, bufY, t);       // r2 -> bufY
  __syncthreads();
  // heads: 64 dot-products of length 256 (8 cls + 56 reg)
  int wv = t >> 6, ln = t & 63;
  for (int task = wv; task < 64; task += 4) {
    float p;
    if (task < 8) {
      float4 yv = *(const float4*)&bufX[task][ln * 4];
      float4 w4 = ((const float4*)Wc3)[ln];
      p = yv.x * w4.x + yv.y * w4.y + yv.z * w4.z + yv.w * w4.w;
    } else {
      int i = task - 8, row = i / 7, j = i % 7;
      float4 yv = *(const float4*)&bufY[row][ln * 4];
      float4 w4 = ((const float4*)(Wr3 + j * 256))[ln];
      p = yv.x * w4.x + yv.y * w4.y + yv.z * w4.z + yv.w * w4.w;
    }
#pragma unroll
    for (int off = 32; off > 0; off >>= 1) p += __shfl_xor(p, off, 64);
    if (ln == 0) hd[task] = p;
  }
  __syncthreads();
  if (t < 8) {
    int m = bid * 8 + t;
    float clsv = hd[t] + bc3[0];
    float rg[7];
#pragma unroll
    for (int j = 0; j < 7; ++j) rg[j] = hd[8 + t * 7 + j] + br3[j];
    const float* R = rois + (size_t)m * 7;
    float rx = R[0], ry = R[1], rz = R[2], dxa = R[3], dya = R[4], dza = R[5], ra = R[6];
    float diag = sqrtf(dxa * dxa + dya * dya);
    float x = rg[0] * diag, y = rg[1] * diag, z = rg[2] * dza;
    float ex = expf(rg[3]) * dxa, ey = expf(rg[4]) * dya, ez = expf(rg[5]) * dza;
    float hr = rg[6] + ra;
    float cc = cosf(ra), sn = sinf(ra);
    float xr = x * cc - y * sn, yr = x * sn + y * cc;
    float* O = out + (size_t)m * 9;
    O[0] = clsv; O[1] = xr + rx; O[2] = yr + ry; O[3] = z + rz;
    O[4] = ex; O[5] = ey; O[6] = ez; O[7] = hr; O[8] = rsc[m];
  }
}

// ---------------- launch ----------------
extern "C" void kernel_launch(void* const* d_in, const int* in_sizes, int n_in,
                              void* d_out, int out_size, void* d_ws, size_t ws_size,
                              hipStream_t stream)
{
  const float* rpn_box = (const float*)d_in[0];
  const float* rpn_cls = (const float*)d_in[1];
  const float* pooled  = (const float*)d_in[2];
  const float* Ws1 = (const float*)d_in[3];
  const float* g1  = (const float*)d_in[4];
  const float* b1  = (const float*)d_in[5];
  const float* Ws2 = (const float*)d_in[6];
  const float* g2  = (const float*)d_in[7];
  const float* b2  = (const float*)d_in[8];
  const float* Wc1 = (const float*)d_in[9];
  const float* gc1 = (const float*)d_in[10];
  const float* bc1 = (const float*)d_in[11];
  const float* Wc2 = (const float*)d_in[12];
  const float* gc2 = (const float*)d_in[13];
  const float* bc2 = (const float*)d_in[14];
  const float* Wc3 = (const float*)d_in[15];
  const float* bc3 = (const float*)d_in[16];
  const float* Wr1 = (const float*)d_in[17];
  const float* gr1 = (const float*)d_in[18];
  const float* br1 = (const float*)d_in[19];
  const float* Wr2 = (const float*)d_in[20];
  const float* gr2 = (const float*)d_in[21];
  const float* br2 = (const float*)d_in[22];
  const float* Wr3 = (const float*)d_in[23];
  const float* br3 = (const float*)d_in[24];

  if (ws_size < WS_NEED) return;

  char* ws = (char*)d_ws;
  u32* keys = (u32*)(ws + OF_KEYS);
  float* tbox = (float*)(ws + OF_TBOX);
  float* tsc  = (float*)(ws + OF_TSC);
  float* bx1 = (float*)(ws + OF_BX1);
  float* bx2 = (float*)(ws + OF_BX2);
  float* by1 = (float*)(ws + OF_BY1);
  float* by2 = (float*)(ws + OF_BY2);
  float* bar = (float*)(ws + OF_BAR);
  u32* mask = (u32*)(ws + OF_MASK);
  float* roisb = (float*)(ws + OF_ROIS);
  float* rscb  = (float*)(ws + OF_RSC);
  u32* Bsw = (u32*)(ws + OF_BSW);
  float* Wt = (float*)(ws + OF_WT);
  float* part = (float*)(ws + OF_PART);

  k_prep<<<4736, 256, 0, stream>>>(Ws1, Ws2, Wc1, Wc2, Wr1, Wr2, Bsw, Wt);
  k_prop<<<4, 1024, 0, stream>>>(rpn_cls, rpn_box, keys, tbox, tsc, bx1, bx2, by1, by2, bar);
  k_mask<<<dim3(16, 16, 4), 64, 0, stream>>>(bx1, bx2, by1, by2, bar, mask);
  k_nms<<<4, 64, 0, stream>>>(mask, tbox, tsc, roisb, rscb);
  k_gemm1<<<512, 256, 0, stream>>>(pooled, Bsw, part);
  k_chain<<<256, 256, 0, stream>>>(part, Wt, g1, b1, g2, b2, gc1, bc1, gc2, bc2,
                                   gr1, br1, gr2, br2, Wc3, bc3, Wr3, br3,
                                   roisb, rscb, (float*)d_out);
}

// Round 5
// 296.385 us; speedup vs baseline: 1.6568x; 1.0806x over previous
//
#include <hip/hip_runtime.h>
#include <cstdint>

typedef unsigned int u32;
typedef unsigned long long u64;
typedef unsigned short u16;

#define BATCH 4
#define A_CNT 70400
#define FEAT 27648
#define KSPLIT 16
#define KCHUNK 1728          // FEAT/KSPLIT
#define NTILE_IT 27          // KCHUNK/64

typedef __attribute__((ext_vector_type(8))) short bf16x8;
typedef __attribute__((ext_vector_type(4))) float f32x4;
typedef __attribute__((ext_vector_type(4))) u32 u32x4;

// ---------------- workspace layout ----------------
constexpr size_t OF_KEYS = 0;                         // 4*70400*4 = 1126400
constexpr size_t OF_TBOX = OF_KEYS + 1126400;         // 4*1024*7*4 = 114688
constexpr size_t OF_TSC  = OF_TBOX + 114688;          // 16384
constexpr size_t OF_BX1  = OF_TSC + 16384;
constexpr size_t OF_BX2  = OF_BX1 + 16384;
constexpr size_t OF_BY1  = OF_BX2 + 16384;
constexpr size_t OF_BY2  = OF_BY1 + 16384;
constexpr size_t OF_BAR  = OF_BY2 + 16384;
constexpr size_t OF_MASK = OF_BAR + 16384;            // 4*1024*32*4 = 524288
constexpr size_t OF_ROIS = OF_MASK + 524288;          // 4*512*7*4 = 57344
constexpr size_t OF_RSC  = OF_ROIS + 57344;           // 8192
constexpr size_t OF_BSW  = OF_RSC + 8192;             // 432*32768 = 14155776
constexpr size_t OF_PART = OF_BSW + 14155776;         // 16*2048*256*4 = 33554432
constexpr size_t WS_NEED = OF_PART + 33554432;

// ---------------- helpers ----------------
__device__ __forceinline__ u32 keyOf(float f) {
  u32 u = __float_as_uint(f);
  return (u & 0x80000000u) ? ~u : (u | 0x80000000u);
}
__device__ __forceinline__ float keyToF(u32 k) {
  u32 u = (k & 0x80000000u) ? (k ^ 0x80000000u) : ~k;
  return __uint_as_float(u);
}
__device__ __forceinline__ u16 f2bf(float f) {   // RNE f32 -> bf16
  u32 u = __float_as_uint(f);
  u32 r = 0x7FFFu + ((u >> 16) & 1u);
  return (u16)((u + r) >> 16);
}
__device__ __forceinline__ void gload_lds16(const void* g, void* l) {
  auto gp = reinterpret_cast<const __attribute__((address_space(1))) unsigned int*>(
      reinterpret_cast<uintptr_t>(g));
  auto lp = reinterpret_cast<__attribute__((address_space(3))) unsigned int*>(
      reinterpret_cast<uintptr_t>(l));
  __builtin_amdgcn_global_load_lds(gp, lp, 16, 0, 0);
}
__device__ __forceinline__ u64 shflx64(u64 v, int m) {
  u32 lo = (u32)v, hi = (u32)(v >> 32);
  lo = __shfl_xor(lo, m, 64);
  hi = __shfl_xor(hi, m, 64);
  return ((u64)hi << 32) | lo;
}

// ---------------- fatA: blocks 0-3 proposal pipeline; blocks 4-867 Bsw prep ----------------
__global__ __launch_bounds__(1024) void k_fatA(const float* __restrict__ cls,
    const float* __restrict__ boxes, const float* __restrict__ Ws1,
    u32* __restrict__ keys, float* __restrict__ tbox, float* __restrict__ tsc,
    float* __restrict__ bx1, float* __restrict__ bx2, float* __restrict__ by1,
    float* __restrict__ by2, float* __restrict__ bar, u32* __restrict__ Bsw)
{
  int bid = blockIdx.x;
  int t = threadIdx.x;
  if (bid >= 4) {
    // ---- Bsw prep: Ws1 -> swizzled bf16 tiles ----
    u32 w = (u32)(bid - 4) * 1024u + t;  // u32x4 index (884736 total)
    u32 tile = w >> 11;                  // 2048 u32x4 per 32KB tile
    u32 rem = w & 2047u;
    u32 n = rem >> 3;                    // row 0..255
    u32 pq = (rem & 7u) << 4;            // 16B-aligned byte pos in row
    u32 q0 = pq ^ ((n & 7u) << 4);       // inverse-swizzled logical byte
    u32 col0 = tile * 64u + (q0 >> 1);
    const float* src = Ws1 + (size_t)n * FEAT + col0;
    float4 f0 = *(const float4*)src;
    float4 f1 = *(const float4*)(src + 4);
    u32x4 o;
    o.x = (u32)f2bf(f0.x) | ((u32)f2bf(f0.y) << 16);
    o.y = (u32)f2bf(f0.z) | ((u32)f2bf(f0.w) << 16);
    o.z = (u32)f2bf(f1.x) | ((u32)f2bf(f1.y) << 16);
    o.w = (u32)f2bf(f1.z) | ((u32)f2bf(f1.w) << 16);
    ((u32x4*)Bsw)[w] = o;
    return;
  }
  // ---- proposal: keys + 2-level histogram threshold + compact + sort + geometry ----
  int b = bid;
  __shared__ u64 s[2048];
  __shared__ u32 h8[256], buf[256];
  __shared__ u32 sh_above, cc;
  __shared__ int selb, selk;
  const float* cb = cls + (size_t)b * A_CNT * 3;
  u32* kb = keys + (size_t)b * A_CNT;

  if (t < 256) h8[t] = 0u;
  __syncthreads();
  for (int g = t; g < A_CNT; g += 1024) {
    float s0 = cb[(size_t)g * 3 + 0];
    float s1 = cb[(size_t)g * 3 + 1];
    float s2 = cb[(size_t)g * 3 + 2];
    u32 k = keyOf(fmaxf(s0, fmaxf(s1, s2)));
    kb[g] = k;
    atomicAdd(&h8[k >> 24], 1u);
  }
  __syncthreads();
  if (t < 256) buf[t] = h8[t];
  __syncthreads();
  for (int d = 1; d < 256; d <<= 1) {
    u32 v = (t < 256 && t + d < 256) ? buf[t + d] : 0u;
    __syncthreads();
    if (t < 256) buf[t] += v;
    __syncthreads();
  }
  if (t < 256 && buf[t] >= 1024u && (t == 255 || buf[t + 1] < 1024u)) selb = t;
  __syncthreads();
  int b8 = selb;
  if (t == 0) sh_above = (b8 == 255) ? 0u : buf[b8 + 1];
  if (t < 256) h8[t] = 0u;
  __syncthreads();
  for (int g = t; g < A_CNT; g += 1024) {
    u32 k = kb[g];
    if ((int)(k >> 24) == b8) atomicAdd(&h8[(k >> 16) & 255u], 1u);
  }
  __syncthreads();
  if (t < 256) buf[t] = h8[t];
  __syncthreads();
  for (int d = 1; d < 256; d <<= 1) {
    u32 v = (t < 256 && t + d < 256) ? buf[t + d] : 0u;
    __syncthreads();
    if (t < 256) buf[t] += v;
    __syncthreads();
  }
  u32 above = sh_above;
  if (t < 256 && above + buf[t] >= 1024u &&
      (t == 255 || above + buf[t + 1] < 1024u)) selk = t;
  if (t == 0) cc = 0u;
  __syncthreads();
  u32 kth = ((u32)b8 << 8) | (u32)selk;
  for (int g = t; g < A_CNT; g += 1024) {
    u32 k = kb[g];
    if ((k >> 16) >= kth) {
      u32 pos = atomicAdd(&cc, 1u);
      if (pos < 2048u) s[pos] = ((u64)k << 32) | (u32)(~(u32)g);
    }
  }
  __syncthreads();
  u32 m = cc; if (m > 2048u) m = 2048u;
  for (int e = t; e < 2048; e += 1024) if (e >= (int)m) s[e] = 0ull;
  __syncthreads();
  // ---- hybrid bitonic sort 2048 desc: reg levels (j<=64 via shfl) + LDS passes (j>=128) ----
  {
    u64 v0 = s[2 * t], v1 = s[2 * t + 1];
#pragma unroll
    for (u32 k = 2; k <= 128; k <<= 1) {
      bool desc = ((t & (k >> 1)) == 0);
#pragma unroll
      for (u32 j = (k >> 1); j >= 2; j >>= 1) {
        u32 mm = j >> 1;
        u64 p0 = shflx64(v0, mm);
        u64 p1 = shflx64(v1, mm);
        bool up = ((t & mm) == 0);
        bool mx = (desc == up);
        v0 = mx ? (v0 > p0 ? v0 : p0) : (v0 < p0 ? v0 : p0);
        v1 = mx ? (v1 > p1 ? v1 : p1) : (v1 < p1 ? v1 : p1);
      }
      if (desc ? (v0 < v1) : (v0 > v1)) { u64 tmp = v0; v0 = v1; v1 = tmp; }
    }
    s[2 * t] = v0; s[2 * t + 1] = v1;
    __syncthreads();
    for (u32 k = 256; k <= 2048; k <<= 1) {
      for (u32 j = k >> 1; j >= 128; j >>= 1) {
        for (int e = t; e < 2048; e += 1024) {
          u32 p = (u32)e ^ j;
          if (p > (u32)e) {
            bool d2 = ((e & k) == 0);
            u64 x = s[e], y = s[p];
            if (d2 ? (x < y) : (x > y)) { s[e] = y; s[p] = x; }
          }
        }
        __syncthreads();
      }
      v0 = s[2 * t]; v1 = s[2 * t + 1];
      bool desc = ((t & (k >> 1)) == 0);
#pragma unroll
      for (u32 j = 64; j >= 2; j >>= 1) {
        u32 mm = j >> 1;
        u64 p0 = shflx64(v0, mm);
        u64 p1 = shflx64(v1, mm);
        bool up = ((t & mm) == 0);
        bool mx = (desc == up);
        v0 = mx ? (v0 > p0 ? v0 : p0) : (v0 < p0 ? v0 : p0);
        v1 = mx ? (v1 > p1 ? v1 : p1) : (v1 < p1 ? v1 : p1);
      }
      if (desc ? (v0 < v1) : (v0 > v1)) { u64 tmp = v0; v0 = v1; v1 = tmp; }
      s[2 * t] = v0; s[2 * t + 1] = v1;
      __syncthreads();
    }
  }
  // ---- geometry tail ----
  u64 comp = s[t];
  u32 kk = (u32)(comp >> 32);
  u32 a = ~(u32)(comp & 0xFFFFFFFFull);
  int o = b * 1024 + t;
  tsc[o] = keyToF(kk);
  const float* bp = boxes + ((size_t)b * A_CNT + a) * 7;
  float x = bp[0], y = bp[1], z = bp[2], dx = bp[3], dy = bp[4], dz = bp[5], rr = bp[6];
  float* tb = tbox + (size_t)o * 7;
  tb[0] = x; tb[1] = y; tb[2] = z; tb[3] = dx; tb[4] = dy; tb[5] = dz; tb[6] = rr;
  {
#pragma clang fp contract(off)
    bx1[o] = x - 0.5f * dx; bx2[o] = x + 0.5f * dx;
    by1[o] = y - 0.5f * dy; by2[o] = y + 0.5f * dy;
    bar[o] = dx * dy;
  }
}

// ---------------- fatB: blocks 0-511 GEMM1 (XCD-swizzled split-K); 512-767 IoU masks ----------------
__global__ __launch_bounds__(256) void k_fatB(const float* __restrict__ A,
    const u32* __restrict__ Bsw, float* __restrict__ part,
    const float* __restrict__ bx1, const float* __restrict__ bx2,
    const float* __restrict__ by1, const float* __restrict__ by2,
    const float* __restrict__ bar, u32* __restrict__ mask)
{
  __shared__ u32x4 Alds4[64 * 8];    // 8 KB
  __shared__ u32x4 Blds4[256 * 8];   // 32 KB
  int bid = blockIdx.x;
  if (bid >= 512) {
    // ---- mask path: fat-block = (b, cb, 4 row-blocks) ----
    int mi = bid - 512;
    int b = mi >> 6;
    int cbk = (mi >> 2) & 15;
    int rb0 = (mi & 3) * 4;
    int tt = threadIdx.x;
    int rbi = tt >> 6, ln = tt & 63;
    int r = (rb0 + rbi) * 64 + ln;
    int o = b * 1024, jc0 = cbk * 64;
    __shared__ float cx1[64], cx2[64], cy1[64], cy2[64], car[64];
    if (tt < 64) {
      cx1[tt] = bx1[o + jc0 + tt]; cx2[tt] = bx2[o + jc0 + tt];
      cy1[tt] = by1[o + jc0 + tt]; cy2[tt] = by2[o + jc0 + tt];
      car[tt] = bar[o + jc0 + tt];
    }
    __syncthreads();
    float rx1 = bx1[o + r], rx2 = bx2[o + r], ry1 = by1[o + r], ry2 = by2[o + r], rar = bar[o + r];
    u32 w0 = 0, w1 = 0;
    {
#pragma clang fp contract(off)
      for (int c = 0; c < 64; ++c) {
        int jc = jc0 + c;
        float iw = fminf(rx2, cx2[c]) - fmaxf(rx1, cx1[c]); iw = fmaxf(iw, 0.0f);
        float ih = fminf(ry2, cy2[c]) - fmaxf(ry1, cy1[c]); ih = fmaxf(ih, 0.0f);
        float inter = iw * ih;
        float den = fmaxf(rar + car[c] - inter, 1e-6f);
        float iou = inter / den;
        if ((iou > 0.7f) && (jc > r)) {
          if (c < 32) w0 |= 1u << c; else w1 |= 1u << (c - 32);
        }
      }
    }
    mask[((size_t)(o + r)) * 32 + cbk * 2 + 0] = w0;
    mask[((size_t)(o + r)) * 32 + cbk * 2 + 1] = w1;
    return;
  }
  // ---- GEMM path ----
  char* Alds = (char*)Alds4;
  char* Blds = (char*)Blds4;
  int q = bid >> 3;                    // 0..63
  int ks = (bid & 7) * 2 + (q >> 5);   // XCD-local K-chunk: each XCD holds 2 chunks in L2
  int mt = q & 31;
  int tid = threadIdx.x, lane = tid & 63, wv = tid >> 6;

  f32x4 acc[4][4];
#pragma unroll
  for (int i = 0; i < 4; ++i)
#pragma unroll
    for (int j = 0; j < 4; ++j) acc[i][j] = (f32x4){0.f, 0.f, 0.f, 0.f};

  int am = tid >> 2;
  int ak = (tid & 3) * 16;
  const float* ap_base = A + ((size_t)(mt * 64 + am)) * FEAT + (size_t)ks * KCHUNK + ak;
  int asw = (am & 7) << 4;
  int ac0 = (tid & 3) * 32;
  char* aw0 = Alds + am * 128 + ((ac0) ^ asw);
  char* aw1 = Alds + am * 128 + ((ac0 + 16) ^ asw);
  const char* bsrc_base = (const char*)Bsw + ((size_t)(ks * NTILE_IT)) * 32768 + (wv * 8) * 1024 + lane * 16;
  char* bdst_base = Blds + (wv * 8) * 1024;

  int row16 = lane & 15, kgrp = lane >> 4;
  int aoff[4][2], boff[4][2];
#pragma unroll
  for (int ksub = 0; ksub < 2; ++ksub) {
    int qq = ksub * 64 + kgrp * 16;
#pragma unroll
    for (int mf = 0; mf < 4; ++mf) {
      int row = mf * 16 + row16;
      aoff[mf][ksub] = row * 128 + (qq ^ ((row & 7) << 4));
    }
#pragma unroll
    for (int nf = 0; nf < 4; ++nf) {
      int n = wv * 64 + nf * 16 + row16;
      boff[nf][ksub] = n * 128 + (qq ^ ((n & 7) << 4));
    }
  }

  for (int it = 0; it < NTILE_IT; ++it) {
    const float4* ap = (const float4*)(ap_base + it * 64);
    float4 f0 = ap[0], f1 = ap[1], f2 = ap[2], f3 = ap[3];
    u32x4 c0, c1;
    c0.x = (u32)f2bf(f0.x) | ((u32)f2bf(f0.y) << 16);
    c0.y = (u32)f2bf(f0.z) | ((u32)f2bf(f0.w) << 16);
    c0.z = (u32)f2bf(f1.x) | ((u32)f2bf(f1.y) << 16);
    c0.w = (u32)f2bf(f1.z) | ((u32)f2bf(f1.w) << 16);
    c1.x = (u32)f2bf(f2.x) | ((u32)f2bf(f2.y) << 16);
    c1.y = (u32)f2bf(f2.z) | ((u32)f2bf(f2.w) << 16);
    c1.z = (u32)f2bf(f3.x) | ((u32)f2bf(f3.y) << 16);
    c1.w = (u32)f2bf(f3.z) | ((u32)f2bf(f3.w) << 16);
    *(u32x4*)aw0 = c0;
    *(u32x4*)aw1 = c1;
    const char* bs = bsrc_base + (size_t)it * 32768;
#pragma unroll
    for (int i = 0; i < 8; ++i) gload_lds16(bs + i * 1024, bdst_base + i * 1024);
    __syncthreads();
    bf16x8 af[4][2], bfv[4][2];
#pragma unroll
    for (int ksub = 0; ksub < 2; ++ksub) {
#pragma unroll
      for (int mf = 0; mf < 4; ++mf) af[mf][ksub] = *(const bf16x8*)(Alds + aoff[mf][ksub]);
#pragma unroll
      for (int nf = 0; nf < 4; ++nf) bfv[nf][ksub] = *(const bf16x8*)(Blds + boff[nf][ksub]);
    }
#pragma unroll
    for (int ksub = 0; ksub < 2; ++ksub)
#pragma unroll
      for (int mf = 0; mf < 4; ++mf)
#pragma unroll
        for (int nf = 0; nf < 4; ++nf)
          acc[mf][nf] = __builtin_amdgcn_mfma_f32_16x16x32_bf16(af[mf][ksub], bfv[nf][ksub], acc[mf][nf], 0, 0, 0);
    __syncthreads();
  }
  float* pb = part + (size_t)ks * 524288;
#pragma unroll
  for (int mf = 0; mf < 4; ++mf) {
    int row = mt * 64 + mf * 16 + kgrp * 4;
#pragma unroll
    for (int nf = 0; nf < 4; ++nf) {
      int col = wv * 64 + nf * 16 + row16;
#pragma unroll
      for (int rr = 0; rr < 4; ++rr)
        pb[(size_t)(row + rr) * 256 + col] = acc[mf][nf][rr];
    }
  }
}

// ---------------- chunked sequential greedy NMS + compact to rois ----------------
__global__ __launch_bounds__(64) void k_nms(const u32* __restrict__ mask,
    const float* __restrict__ tbox, const float* __restrict__ tsc,
    float* __restrict__ rois, float* __restrict__ rsc)
{
  int b = blockIdx.x;
  int lane = threadIdx.x;
  int el = lane & 31;
  const u32* M = mask + (size_t)b * 1024 * 32;
  u32 R = 0;
  u32 cur[32], nxt[32];
#pragma unroll
  for (int i = 0; i < 32; ++i) cur[i] = M[(size_t)(i * 32 + el)];
#pragma unroll 1
  for (int c = 0; c < 32; ++c) {
    if (c < 31) {
      int nb = (c + 1) * 1024 + el;
#pragma unroll
      for (int i = 0; i < 32; ++i) nxt[i] = M[(size_t)(nb + i * 32)];
    }
    u32 w = R;
#pragma unroll
    for (int i = 0; i < 32; ++i) w |= ((w >> i) & 1u) ? 0u : cur[i];
    u32 wfin = __shfl(w, c, 64);
#pragma unroll
    for (int i = 0; i < 32; ++i) R |= ((wfin >> i) & 1u) ? 0u : cur[i];
#pragma unroll
    for (int i = 0; i < 32; ++i) cur[i] = nxt[i];
  }
  u32 keepw = (lane < 32) ? ~R : 0u;
  int c = __popc(keepw);
  int pre = c;
  for (int d = 1; d < 64; d <<= 1) {
    int v = __shfl_up(pre, d, 64);
    if (lane >= d) pre += v;
  }
  int total = __shfl(pre, 31, 64);
  int base = pre - c;
  if (lane < 32) {
    u32 w = keepw;
    int rank = base;
    while (w) {
      int bit = __ffs(w) - 1;
      w &= w - 1;
      if (rank < 512) {
        int r = lane * 32 + bit;
        const float* tb = tbox + ((size_t)b * 1024 + r) * 7;
        float* rp = rois + ((size_t)b * 512 + rank) * 7;
        rp[0] = tb[0]; rp[1] = tb[1]; rp[2] = tb[2]; rp[3] = tb[3];
        rp[4] = tb[4]; rp[5] = tb[5]; rp[6] = tb[6];
        rsc[b * 512 + rank] = tsc[b * 1024 + r];
      }
      rank++;
    }
  }
  for (int z = total + lane; z < 512; z += 64) {
    float* rp = rois + ((size_t)b * 512 + z) * 7;
    rp[0] = rp[1] = rp[2] = rp[3] = rp[4] = rp[5] = rp[6] = 0.0f;
    rsc[b * 512 + z] = 0.0f;
  }
}

// ---------------- one 256x256 layer (4 rows per thread-half) + BN + ReLU ----------------
__device__ __forceinline__ void layer4(const float (*IN)[256], const float* __restrict__ W,
    const float* __restrict__ g, const float* __restrict__ bb, float (*OUT)[256], int t, int h)
{
  float acc[4] = {0, 0, 0, 0};
  const float* Wrow = W + (size_t)t * 256;
  for (int k = 0; k < 256; k += 4) {
    float4 w4 = *(const float4*)&Wrow[k];
#pragma unroll
    for (int r = 0; r < 4; ++r) {
      float4 xv = *(const float4*)&IN[h * 4 + r][k];
      acc[r] = fmaf(xv.x, w4.x, acc[r]);
      acc[r] = fmaf(xv.y, w4.y, acc[r]);
      acc[r] = fmaf(xv.z, w4.z, acc[r]);
      acc[r] = fmaf(xv.w, w4.w, acc[r]);
    }
  }
  float sc = g[t] / sqrtf(1.0f + 1e-5f);
  float bv = bb[t];
#pragma unroll
  for (int r = 0; r < 4; ++r)
    OUT[h * 4 + r][t] = fmaxf(fmaf(acc[r], sc, bv), 0.0f);
}

// ---------------- fused head chain (512 threads): reduce -> x2 -> {c1,r1} -> {c2,r2} -> heads+decode ----------------
__global__ __launch_bounds__(512) void k_chain(const float* __restrict__ part,
    const float* __restrict__ Ws2, const float* __restrict__ Wc1, const float* __restrict__ Wc2,
    const float* __restrict__ Wr1, const float* __restrict__ Wr2,
    const float* __restrict__ g1, const float* __restrict__ b1,
    const float* __restrict__ g2, const float* __restrict__ b2,
    const float* __restrict__ gc1, const float* __restrict__ bc1,
    const float* __restrict__ gc2, const float* __restrict__ bc2,
    const float* __restrict__ gr1, const float* __restrict__ br1,
    const float* __restrict__ gr2, const float* __restrict__ br2,
    const float* __restrict__ Wc3, const float* __restrict__ bc3,
    const float* __restrict__ Wr3, const float* __restrict__ br3,
    const float* __restrict__ rois, const float* __restrict__ rsc,
    float* __restrict__ out)
{
  int bid = blockIdx.x, tid = threadIdx.x;
  int t = tid & 255, h = tid >> 8;        // h: row-half (rows h*4..h*4+3)
  __shared__ __align__(16) float bufX[8][256];
  __shared__ __align__(16) float bufY[8][256];
  __shared__ __align__(16) float bufC[8][256];
  __shared__ __align__(16) float bufR[8][256];
  __shared__ float hd[64];
  {
    float sc = g1[t] / sqrtf(1.0f + 1e-5f);
    float bv = b1[t];
#pragma unroll
    for (int r = 0; r < 4; ++r) {
      int row = h * 4 + r;
      float s = 0.f;
#pragma unroll
      for (int ks = 0; ks < KSPLIT; ++ks)
        s += part[(size_t)ks * 524288 + (size_t)(bid * 8 + row) * 256 + t];
      bufX[row][t] = fmaxf(fmaf(s, sc, bv), 0.0f);
    }
  }
  __syncthreads();
  layer4(bufX, Ws2, g2, b2, bufY, t, h);          // x2
  __syncthreads();
  layer4(bufY, Wc1, gc1, bc1, bufC, t, h);        // c1
  layer4(bufY, Wr1, gr1, br1, bufR, t, h);        // r1
  __syncthreads();
  layer4(bufC, Wc2, gc2, bc2, bufX, t, h);        // c2 -> bufX
  layer4(bufR, Wr2, gr2, br2, bufY, t, h);        // r2 -> bufY
  __syncthreads();
  int wv = tid >> 6, ln = tid & 63;
  for (int task = wv; task < 64; task += 8) {
    float p;
    if (task < 8) {
      float4 yv = *(const float4*)&bufX[task][ln * 4];
      float4 w4 = ((const float4*)Wc3)[ln];
      p = yv.x * w4.x + yv.y * w4.y + yv.z * w4.z + yv.w * w4.w;
    } else {
      int i = task - 8, row = i / 7, j = i % 7;
      float4 yv = *(const float4*)&bufY[row][ln * 4];
      float4 w4 = ((const float4*)(Wr3 + j * 256))[ln];
      p = yv.x * w4.x + yv.y * w4.y + yv.z * w4.z + yv.w * w4.w;
    }
#pragma unroll
    for (int off = 32; off > 0; off >>= 1) p += __shfl_xor(p, off, 64);
    if (ln == 0) hd[task] = p;
  }
  __syncthreads();
  if (tid < 8) {
    int m = bid * 8 + tid;
    float clsv = hd[tid] + bc3[0];
    float rg[7];
#pragma unroll
    for (int j = 0; j < 7; ++j) rg[j] = hd[8 + tid * 7 + j] + br3[j];
    const float* R = rois + (size_t)m * 7;
    float rx = R[0], ry = R[1], rz = R[2], dxa = R[3], dya = R[4], dza = R[5], ra = R[6];
    float diag = sqrtf(dxa * dxa + dya * dya);
    float x = rg[0] * diag, y = rg[1] * diag, z = rg[2] * dza;
    float ex = expf(rg[3]) * dxa, ey = expf(rg[4]) * dya, ez = expf(rg[5]) * dza;
    float hr = rg[6] + ra;
    float cc = cosf(ra), sn = sinf(ra);
    float xr = x * cc - y * sn, yr = x * sn + y * cc;
    float* O = out + (size_t)m * 9;
    O[0] = clsv; O[1] = xr + rx; O[2] = yr + ry; O[3] = z + rz;
    O[4] = ex; O[5] = ey; O[6] = ez; O[7] = hr; O[8] = rsc[m];
  }
}

// ---------------- launch ----------------
extern "C" void kernel_launch(void* const* d_in, const int* in_sizes, int n_in,
                              void* d_out, int out_size, void* d_ws, size_t ws_size,
                              hipStream_t stream)
{
  const float* rpn_box = (const float*)d_in[0];
  const float* rpn_cls = (const float*)d_in[1];
  const float* pooled  = (const float*)d_in[2];
  const float* Ws1 = (const float*)d_in[3];
  const float* g1  = (const float*)d_in[4];
  const float* b1  = (const float*)d_in[5];
  const float* Ws2 = (const float*)d_in[6];
  const float* g2  = (const float*)d_in[7];
  const float* b2  = (const float*)d_in[8];
  const float* Wc1 = (const float*)d_in[9];
  const float* gc1 = (const float*)d_in[10];
  const float* bc1 = (const float*)d_in[11];
  const float* Wc2 = (const float*)d_in[12];
  const float* gc2 = (const float*)d_in[13];
  const float* bc2 = (const float*)d_in[14];
  const float* Wc3 = (const float*)d_in[15];
  const float* bc3 = (const float*)d_in[16];
  const float* Wr1 = (const float*)d_in[17];
  const float* gr1 = (const float*)d_in[18];
  const float* br1 = (const float*)d_in[19];
  const float* Wr2 = (const float*)d_in[20];
  const float* gr2 = (const float*)d_in[21];
  const float* br2 = (const float*)d_in[22];
  const float* Wr3 = (const float*)d_in[23];
  const float* br3 = (const float*)d_in[24];

  if (ws_size < WS_NEED) return;

  char* ws = (char*)d_ws;
  u32* keys = (u32*)(ws + OF_KEYS);
  float* tbox = (float*)(ws + OF_TBOX);
  float* tsc  = (float*)(ws + OF_TSC);
  float* bx1 = (float*)(ws + OF_BX1);
  float* bx2 = (float*)(ws + OF_BX2);
  float* by1 = (float*)(ws + OF_BY1);
  float* by2 = (float*)(ws + OF_BY2);
  float* bar = (float*)(ws + OF_BAR);
  u32* mask = (u32*)(ws + OF_MASK);
  float* roisb = (float*)(ws + OF_ROIS);
  float* rscb  = (float*)(ws + OF_RSC);
  u32* Bsw = (u32*)(ws + OF_BSW);
  float* part = (float*)(ws + OF_PART);

  k_fatA<<<868, 1024, 0, stream>>>(rpn_cls, rpn_box, Ws1, keys, tbox, tsc,
                                   bx1, bx2, by1, by2, bar, Bsw);
  k_fatB<<<768, 256, 0, stream>>>(pooled, Bsw, part, bx1, bx2, by1, by2, bar, mask);
  k_nms<<<4, 64, 0, stream>>>(mask, tbox, tsc, roisb, rscb);
  k_chain<<<256, 512, 0, stream>>>(part, Ws2, Wc1, Wc2, Wr1, Wr2,
                                   g1, b1, g2, b2, gc1, bc1, gc2, bc2,
                                   gr1, br1, gr2, br2, Wc3, bc3, Wr3, br3,
                                   roisb, rscb, (float*)d_out);
}